// Round 6
// baseline (595.253 us; speedup 1.0000x reference)
//
#include <hip/hip_runtime.h>
#include <hip/hip_bf16.h>

// Problem constants
#define BB 2
#define LL 2048
#define DD 1024
#define HH 16
#define FD 16
#define HD 64
#define EPS 1e-5f
#define RQKV 1536   // fused QKV row stride (256 Q + 256 K + 1024 V)
#define S2SCALE 512.0f  // keeps s^2 in fp16 normal range through the LDS round-trip
#define NFIX 4      // first NFIX positions per (b,h) recomputed in fp32 (low-z rows)

typedef __attribute__((ext_vector_type(4))) float f32x4;
typedef __attribute__((ext_vector_type(8))) _Float16 f16x8;
typedef __attribute__((ext_vector_type(4))) _Float16 f16x4;

// ---------------------------------------------------------------------------
// Transpose + cast: src fp32 [K][N] -> dst fp16 [N][K]. Grid (N/32, K/32).
// ---------------------------------------------------------------------------
__global__ __launch_bounds__(256) void transpose_cast(
    const float* __restrict__ src, _Float16* __restrict__ dst, int K, int N) {
  __shared__ _Float16 s[32][40];
  const int n0 = blockIdx.x * 32, k0 = blockIdx.y * 32;
  const int tid = threadIdx.x;
  {
    int r = tid >> 3, c = (tid & 7) * 4;
    float4 v = *(const float4*)(src + (size_t)(k0 + r) * N + n0 + c);
    f16x4 p = {(_Float16)v.x, (_Float16)v.y, (_Float16)v.z, (_Float16)v.w};
    *(f16x4*)&s[r][c] = p;
  }
  __syncthreads();
  {
    int n = tid >> 3, kk = (tid & 7) * 4;
    f16x4 o = {s[kk + 0][n], s[kk + 1][n], s[kk + 2][n], s[kk + 3][n]};
    *(f16x4*)(dst + (size_t)(n0 + n) * K + k0 + kk) = o;
  }
}

// ---------------------------------------------------------------------------
// MFMA GEMM: C[M,N] = A[M,K] @ Bt[N,K]^T. 128x128 tile, BK=32, 4 waves.
// ---------------------------------------------------------------------------
template <typename AT, typename OutT>
__global__ __launch_bounds__(256) void gemm_tn(
    const AT* __restrict__ A, const _Float16* __restrict__ Bt,
    OutT* __restrict__ C, int M, int N, int K) {
  constexpr int LDT = 40;
  __shared__ __attribute__((aligned(16))) _Float16 sA[128 * LDT];
  __shared__ __attribute__((aligned(16))) _Float16 sB[128 * LDT];
  const int tid = threadIdx.x;
  const int m0 = blockIdx.y * 128, n0 = blockIdx.x * 128;
  const int w = tid >> 6, lane = tid & 63, quad = lane >> 4, l16 = lane & 15;
  const int wm = (w >> 1) * 64, wn = (w & 1) * 64;

  const int sr = tid >> 1, sh = (tid & 1) * 16;
  const AT* Ag = A + (size_t)(m0 + sr) * K + sh;
  const _Float16* Bg = Bt + (size_t)(n0 + sr) * K + sh;
  _Float16* sAw = &sA[sr * LDT + sh];
  _Float16* sBw = &sB[sr * LDT + sh];

  f32x4 acc[4][4];
#pragma unroll
  for (int i = 0; i < 4; i++)
#pragma unroll
    for (int j = 0; j < 4; j++) acc[i][j] = (f32x4){0.f, 0.f, 0.f, 0.f};

  for (int k0 = 0; k0 < K; k0 += 32) {
    __syncthreads();
    if constexpr (sizeof(AT) == 4) {
      float4 a0 = *(const float4*)(Ag + k0);
      float4 a1 = *(const float4*)(Ag + k0 + 4);
      float4 a2 = *(const float4*)(Ag + k0 + 8);
      float4 a3 = *(const float4*)(Ag + k0 + 12);
      f16x8 p0 = {(_Float16)a0.x, (_Float16)a0.y, (_Float16)a0.z, (_Float16)a0.w,
                  (_Float16)a1.x, (_Float16)a1.y, (_Float16)a1.z, (_Float16)a1.w};
      f16x8 p1 = {(_Float16)a2.x, (_Float16)a2.y, (_Float16)a2.z, (_Float16)a2.w,
                  (_Float16)a3.x, (_Float16)a3.y, (_Float16)a3.z, (_Float16)a3.w};
      *(f16x8*)sAw = p0;
      *(f16x8*)(sAw + 8) = p1;
    } else {
      *(f16x8*)sAw = *(const f16x8*)(Ag + k0);
      *(f16x8*)(sAw + 8) = *(const f16x8*)(Ag + k0 + 8);
    }
    *(f16x8*)sBw = *(const f16x8*)(Bg + k0);
    *(f16x8*)(sBw + 8) = *(const f16x8*)(Bg + k0 + 8);
    __syncthreads();

    f16x8 af[4], bf[4];
#pragma unroll
    for (int i = 0; i < 4; i++)
      af[i] = *(const f16x8*)&sA[(wm + i * 16 + l16) * LDT + quad * 8];
#pragma unroll
    for (int j = 0; j < 4; j++)
      bf[j] = *(const f16x8*)&sB[(wn + j * 16 + l16) * LDT + quad * 8];
#pragma unroll
    for (int i = 0; i < 4; i++)
#pragma unroll
      for (int j = 0; j < 4; j++)
        acc[i][j] = __builtin_amdgcn_mfma_f32_16x16x32_f16(af[i], bf[j], acc[i][j], 0, 0, 0);
  }

#pragma unroll
  for (int i = 0; i < 4; i++)
#pragma unroll
    for (int j = 0; j < 4; j++)
#pragma unroll
      for (int r = 0; r < 4; r++) {
        const int row = m0 + wm + i * 16 + quad * 4 + r;
        const int col = n0 + wn + j * 16 + l16;
        C[(size_t)row * N + col] = (OutT)acc[i][j][r];
      }
}

// ---------------------------------------------------------------------------
// MFMA causal quadratic attention (fp16, S2 scaled by 512).
// QKV: fp16 [B*L,1536] fused. O: fp16 [B*L,1024], divided by (z+eps).
// ---------------------------------------------------------------------------
#define SK_STRIDE 24
#define SV_STRIDE 72
#define SS_STRIDE 72

__global__ __launch_bounds__(256) void attn_mfma(
    const _Float16* __restrict__ QKV, _Float16* __restrict__ O) {
  __shared__ __attribute__((aligned(16))) _Float16 sK[64 * SK_STRIDE];
  __shared__ __attribute__((aligned(16))) _Float16 sVt[64 * SV_STRIDE];
  __shared__ __attribute__((aligned(16))) _Float16 sS2[4 * 16 * SS_STRIDE];

  const int bh = blockIdx.y;
  const int b = bh >> 4, h = bh & 15;
  const int q0 = blockIdx.x * 64;
  const int tid = threadIdx.x;
  const int w = tid >> 6;
  const int lane = tid & 63;
  const int quad = lane >> 4;
  const int l16 = lane & 15;

  f16x8 qfrag = {};
  if (quad < 2) {
    const _Float16* qp =
        QKV + (size_t)(b * LL + q0 + w * 16 + l16) * RQKV + h * FD + quad * 8;
    qfrag = *(const f16x8*)qp;
  }

  f32x4 oacc[4];
#pragma unroll
  for (int nt = 0; nt < 4; nt++) oacc[nt] = (f32x4){0.f, 0.f, 0.f, 0.f};
  float zpart[4] = {0.f, 0.f, 0.f, 0.f};

  _Float16* sS2w = sS2 + w * 16 * SS_STRIDE;
  const int gq_base = q0 + w * 16;

  const int ktiles = blockIdx.x + 1;
  for (int kt = 0; kt < ktiles; kt++) {
    const int k0 = kt * 64;
    __syncthreads();
    {
      int key = tid >> 2, fg = (tid & 3) * 4;
      const _Float16* kp =
          QKV + (size_t)(b * LL + k0 + key) * RQKV + 256 + h * FD + fg;
      *(uint2*)&sK[key * SK_STRIDE + fg] = *(const uint2*)kp;
    }
    {
      int key = tid >> 2, c0 = (tid & 3) * 16;
      const _Float16* vp =
          QKV + (size_t)(b * LL + k0 + key) * RQKV + 512 + h * HD + c0;
      _Float16 tmp[16];
      *(f16x8*)&tmp[0] = *(const f16x8*)vp;
      *(f16x8*)&tmp[8] = *(const f16x8*)(vp + 8);
#pragma unroll
      for (int i = 0; i < 16; i++) sVt[(c0 + i) * SV_STRIDE + key] = tmp[i];
    }
    __syncthreads();

    f16x8 kf[4];
#pragma unroll
    for (int nt = 0; nt < 4; nt++) {
      f16x8 f = {};
      if (quad < 2) f = *(const f16x8*)&sK[(nt * 16 + l16) * SK_STRIDE + quad * 8];
      kf[nt] = f;
    }

#pragma unroll
    for (int nt = 0; nt < 4; nt++) {
      f32x4 s = __builtin_amdgcn_mfma_f32_16x16x32_f16(
          qfrag, kf[nt], (f32x4){0.f, 0.f, 0.f, 0.f}, 0, 0, 0);
      const int gk = k0 + nt * 16 + l16;
#pragma unroll
      for (int r = 0; r < 4; r++) {
        float sv = s[r] * 0.0625f;
        sv = sv * sv * S2SCALE;
        const int gq = gq_base + quad * 4 + r;
        sv = (gk <= gq) ? sv : 0.0f;
        zpart[r] += sv;
        sS2w[(quad * 4 + r) * SS_STRIDE + nt * 16 + l16] = (_Float16)sv;
      }
    }
    __asm__ volatile("s_waitcnt lgkmcnt(0)" ::: "memory");

    f16x8 af0 = *(const f16x8*)&sS2w[l16 * SS_STRIDE + quad * 8];
    f16x8 af1 = *(const f16x8*)&sS2w[l16 * SS_STRIDE + 32 + quad * 8];

#pragma unroll
    for (int nt = 0; nt < 4; nt++) {
      f16x8 vf0 = *(const f16x8*)&sVt[(nt * 16 + l16) * SV_STRIDE + quad * 8];
      f16x8 vf1 = *(const f16x8*)&sVt[(nt * 16 + l16) * SV_STRIDE + 32 + quad * 8];
      oacc[nt] = __builtin_amdgcn_mfma_f32_16x16x32_f16(af0, vf0, oacc[nt], 0, 0, 0);
      oacc[nt] = __builtin_amdgcn_mfma_f32_16x16x32_f16(af1, vf1, oacc[nt], 0, 0, 0);
    }
  }

  float rz[4];
#pragma unroll
  for (int r = 0; r < 4; r++) {
    float t = zpart[r];
    t += __shfl_xor(t, 1);
    t += __shfl_xor(t, 2);
    t += __shfl_xor(t, 4);
    t += __shfl_xor(t, 8);
    rz[r] = 1.0f / (t + S2SCALE * EPS);
  }
#pragma unroll
  for (int nt = 0; nt < 4; nt++) {
#pragma unroll
    for (int r = 0; r < 4; r++) {
      const int gq = gq_base + quad * 4 + r;
      O[(size_t)(b * LL + gq) * (HH * HD) + h * HD + nt * 16 + l16] =
          (_Float16)(oacc[nt][r] * rz[r]);
    }
  }
}

// ---------------------------------------------------------------------------
// fp32-exact recompute of the first NFIX positions per (b,h) (low-z rows where
// the s^2/(z+eps) ratio amplifies absolute fp16 rounding of q,k).
// Round-6 restructure: grid 32 -> 128 blocks (one per (b,h,p)); each thread
// owns one weight COLUMN and accumulates all rows 0..p at once from LDS-staged
// hs (W load amortized, LDS reads are broadcasts); d-loop unrolled for MLP.
// ---------------------------------------------------------------------------
__global__ __launch_bounds__(256) void fix_early(
    const float* __restrict__ hs, const float* __restrict__ Wq,
    const float* __restrict__ Wk, const float* __restrict__ Wv,
    _Float16* __restrict__ Oatt) {
  const int p = blockIdx.x & (NFIX - 1);
  const int bh = blockIdx.x >> 2;
  const int b = bh >> 4, h = bh & 15;
  const int tid = threadIdx.x;

  __shared__ float sHS[NFIX][DD];
  __shared__ float sQ[16], sKs[NFIX][16], sV[NFIX][64];

  // stage hs rows 0..p (k/v need all rows <= p; q needs row p)
  for (int i = tid; i < (p + 1) * (DD / 4); i += 256) {
    int r = i / (DD / 4), c = (i % (DD / 4)) * 4;
    *(float4*)&sHS[r][c] = *(const float4*)(hs + (size_t)(b * LL + r) * DD + c);
  }
  __syncthreads();

  // Projections: thread c (0..95) owns one output column.
  //   c<16:   q col  h*16+c      (row p only)
  //   c<32:   k col  h*16+(c-16) (rows 0..p)
  //   c<96:   v col  h*64+(c-32) (rows 0..p)
  if (tid < 96) {
    const float* W;
    int col, ncol;
    bool isq = tid < 16;
    if (isq) { W = Wq; col = h * 16 + tid; ncol = 256; }
    else if (tid < 32) { W = Wk; col = h * 16 + (tid - 16); ncol = 256; }
    else { W = Wv; col = h * 64 + (tid - 32); ncol = 1024; }

    float acc0 = 0.f, acc1 = 0.f, acc2 = 0.f, acc3 = 0.f;
    if (isq) {
#pragma unroll 8
      for (int d = 0; d < DD; d++) acc0 += sHS[p][d] * W[(size_t)d * ncol + col];
      sQ[tid] = acc0;
    } else {
#pragma unroll 8
      for (int d = 0; d < DD; d++) {
        float wv = W[(size_t)d * ncol + col];
        acc0 += sHS[0][d] * wv;
        if (p >= 1) acc1 += sHS[1][d] * wv;
        if (p >= 2) acc2 += sHS[2][d] * wv;
        if (p >= 3) acc3 += sHS[3][d] * wv;
      }
      float a[4] = {acc0, acc1, acc2, acc3};
      if (tid < 32) {
        for (int r = 0; r <= p; r++) sKs[r][tid - 16] = a[r];
      } else {
        for (int r = 0; r <= p; r++) sV[r][tid - 32] = a[r];
      }
    }
  }
  __syncthreads();

  // o_p[d], one thread per d (exact fp32 ratio)
  if (tid < 64) {
    const int d = tid;
    float num = 0.f, z = 0.f;
    for (int j = 0; j <= p; j++) {
      float s = 0.f;
#pragma unroll
      for (int f = 0; f < 16; f++) s += sQ[f] * sKs[j][f];
      s *= 0.25f;  // FD^-0.5 on q
      s = s * s;
      z += s;
      num += s * sV[j][d];
    }
    Oatt[(size_t)(b * LL + p) * (HH * HD) + h * HD + d] =
        (_Float16)(num / (z + EPS));
  }
}

// ---------------------------------------------------------------------------
// Launch
// ---------------------------------------------------------------------------
extern "C" void kernel_launch(void* const* d_in, const int* in_sizes, int n_in,
                              void* d_out, int out_size, void* d_ws, size_t ws_size,
                              hipStream_t stream) {
  const float* hs = (const float*)d_in[0];  // [4096, 1024]
  const float* Wq = (const float*)d_in[1];  // [1024, 256]
  const float* Wk = (const float*)d_in[2];  // [1024, 256]
  const float* Wv = (const float*)d_in[3];  // [1024, 1024]
  const float* Wo = (const float*)d_in[4];  // [1024, 1024]
  float* out = (float*)d_out;               // [4096, 1024]

  char* ws = (char*)d_ws;
  _Float16* WqkvT = (_Float16*)ws;                    // [1536][1024] = 3 MiB
  _Float16* WoT   = (_Float16*)(ws + (3ull << 20));   // [1024][1024] = 2 MiB
  _Float16* QKV   = (_Float16*)(ws + (8ull << 20));   // [4096][1536] = 12 MiB
  _Float16* Oatt  = (_Float16*)(ws + (20ull << 20));  // [4096][1024] = 8 MiB

  const int M = BB * LL;  // 4096

  transpose_cast<<<dim3(256 / 32, DD / 32), 256, 0, stream>>>(Wq, WqkvT, DD, 256);
  transpose_cast<<<dim3(256 / 32, DD / 32), 256, 0, stream>>>(Wk, WqkvT + 256 * DD, DD, 256);
  transpose_cast<<<dim3(DD / 32, DD / 32), 256, 0, stream>>>(Wv, WqkvT + 512 * DD, DD, DD);
  transpose_cast<<<dim3(DD / 32, DD / 32), 256, 0, stream>>>(Wo, WoT, DD, DD);

  gemm_tn<float, _Float16><<<dim3(RQKV / 128, M / 128), 256, 0, stream>>>(
      hs, WqkvT, QKV, M, RQKV, DD);

  attn_mfma<<<dim3(LL / 64, BB * HH), 256, 0, stream>>>(QKV, Oatt);

  // fp32-exact first NFIX positions per (b,h); one block per (b,h,p)
  fix_early<<<dim3(BB * HH * NFIX), 256, 0, stream>>>(hs, Wq, Wk, Wv, Oatt);

  gemm_tn<_Float16, float><<<dim3(DD / 128, M / 128), 256, 0, stream>>>(
      Oatt, WoT, out, M, DD, DD);
}

// Round 7
// 243.332 us; speedup vs baseline: 2.4463x; 2.4463x over previous
//
#include <hip/hip_runtime.h>
#include <hip/hip_bf16.h>

// Problem constants
#define BB 2
#define LL 2048
#define DD 1024
#define HH 16
#define FD 16
#define HD 64
#define EPS 1e-5f
#define RQKV 1536   // fused QKV row stride (256 Q + 256 K + 1024 V)
#define S2SCALE 512.0f  // keeps s^2 in fp16 normal range through the LDS round-trip
#define NFIX 4      // first NFIX positions per (b,h) recomputed in fp32 (low-z rows)

typedef __attribute__((ext_vector_type(4))) float f32x4;
typedef __attribute__((ext_vector_type(8))) _Float16 f16x8;
typedef __attribute__((ext_vector_type(4))) _Float16 f16x4;

// ---------------------------------------------------------------------------
// Transpose + cast: src fp32 [K][N] -> dst fp16 [N][K]. Grid (N/32, K/32).
// ---------------------------------------------------------------------------
__global__ __launch_bounds__(256) void transpose_cast(
    const float* __restrict__ src, _Float16* __restrict__ dst, int K, int N) {
  __shared__ _Float16 s[32][40];
  const int n0 = blockIdx.x * 32, k0 = blockIdx.y * 32;
  const int tid = threadIdx.x;
  {
    int r = tid >> 3, c = (tid & 7) * 4;
    float4 v = *(const float4*)(src + (size_t)(k0 + r) * N + n0 + c);
    f16x4 p = {(_Float16)v.x, (_Float16)v.y, (_Float16)v.z, (_Float16)v.w};
    *(f16x4*)&s[r][c] = p;
  }
  __syncthreads();
  {
    int n = tid >> 3, kk = (tid & 7) * 4;
    f16x4 o = {s[kk + 0][n], s[kk + 1][n], s[kk + 2][n], s[kk + 3][n]};
    *(f16x4*)(dst + (size_t)(n0 + n) * K + k0 + kk) = o;
  }
}

// ---------------------------------------------------------------------------
// MFMA GEMM: C[M,N] = A[M,K] @ Bt[N,K]^T. 128x128 tile, BK=32, 4 waves.
// ---------------------------------------------------------------------------
template <typename AT, typename OutT>
__global__ __launch_bounds__(256) void gemm_tn(
    const AT* __restrict__ A, const _Float16* __restrict__ Bt,
    OutT* __restrict__ C, int M, int N, int K) {
  constexpr int LDT = 40;
  __shared__ __attribute__((aligned(16))) _Float16 sA[128 * LDT];
  __shared__ __attribute__((aligned(16))) _Float16 sB[128 * LDT];
  const int tid = threadIdx.x;
  const int m0 = blockIdx.y * 128, n0 = blockIdx.x * 128;
  const int w = tid >> 6, lane = tid & 63, quad = lane >> 4, l16 = lane & 15;
  const int wm = (w >> 1) * 64, wn = (w & 1) * 64;

  const int sr = tid >> 1, sh = (tid & 1) * 16;
  const AT* Ag = A + (size_t)(m0 + sr) * K + sh;
  const _Float16* Bg = Bt + (size_t)(n0 + sr) * K + sh;
  _Float16* sAw = &sA[sr * LDT + sh];
  _Float16* sBw = &sB[sr * LDT + sh];

  f32x4 acc[4][4];
#pragma unroll
  for (int i = 0; i < 4; i++)
#pragma unroll
    for (int j = 0; j < 4; j++) acc[i][j] = (f32x4){0.f, 0.f, 0.f, 0.f};

  for (int k0 = 0; k0 < K; k0 += 32) {
    __syncthreads();
    if constexpr (sizeof(AT) == 4) {
      float4 a0 = *(const float4*)(Ag + k0);
      float4 a1 = *(const float4*)(Ag + k0 + 4);
      float4 a2 = *(const float4*)(Ag + k0 + 8);
      float4 a3 = *(const float4*)(Ag + k0 + 12);
      f16x8 p0 = {(_Float16)a0.x, (_Float16)a0.y, (_Float16)a0.z, (_Float16)a0.w,
                  (_Float16)a1.x, (_Float16)a1.y, (_Float16)a1.z, (_Float16)a1.w};
      f16x8 p1 = {(_Float16)a2.x, (_Float16)a2.y, (_Float16)a2.z, (_Float16)a2.w,
                  (_Float16)a3.x, (_Float16)a3.y, (_Float16)a3.z, (_Float16)a3.w};
      *(f16x8*)sAw = p0;
      *(f16x8*)(sAw + 8) = p1;
    } else {
      *(f16x8*)sAw = *(const f16x8*)(Ag + k0);
      *(f16x8*)(sAw + 8) = *(const f16x8*)(Ag + k0 + 8);
    }
    *(f16x8*)sBw = *(const f16x8*)(Bg + k0);
    *(f16x8*)(sBw + 8) = *(const f16x8*)(Bg + k0 + 8);
    __syncthreads();

    f16x8 af[4], bf[4];
#pragma unroll
    for (int i = 0; i < 4; i++)
      af[i] = *(const f16x8*)&sA[(wm + i * 16 + l16) * LDT + quad * 8];
#pragma unroll
    for (int j = 0; j < 4; j++)
      bf[j] = *(const f16x8*)&sB[(wn + j * 16 + l16) * LDT + quad * 8];
#pragma unroll
    for (int i = 0; i < 4; i++)
#pragma unroll
      for (int j = 0; j < 4; j++)
        acc[i][j] = __builtin_amdgcn_mfma_f32_16x16x32_f16(af[i], bf[j], acc[i][j], 0, 0, 0);
  }

#pragma unroll
  for (int i = 0; i < 4; i++)
#pragma unroll
    for (int j = 0; j < 4; j++)
#pragma unroll
      for (int r = 0; r < 4; r++) {
        const int row = m0 + wm + i * 16 + quad * 4 + r;
        const int col = n0 + wn + j * 16 + l16;
        C[(size_t)row * N + col] = (OutT)acc[i][j][r];
      }
}

// ---------------------------------------------------------------------------
// MFMA causal quadratic attention (fp16, S2 scaled by 512).
// QKV: fp16 [B*L,1536] fused. O: fp16 [B*L,1024], divided by (z+eps).
// ---------------------------------------------------------------------------
#define SK_STRIDE 24
#define SV_STRIDE 72
#define SS_STRIDE 72

__global__ __launch_bounds__(256) void attn_mfma(
    const _Float16* __restrict__ QKV, _Float16* __restrict__ O) {
  __shared__ __attribute__((aligned(16))) _Float16 sK[64 * SK_STRIDE];
  __shared__ __attribute__((aligned(16))) _Float16 sVt[64 * SV_STRIDE];
  __shared__ __attribute__((aligned(16))) _Float16 sS2[4 * 16 * SS_STRIDE];

  const int bh = blockIdx.y;
  const int b = bh >> 4, h = bh & 15;
  const int q0 = blockIdx.x * 64;
  const int tid = threadIdx.x;
  const int w = tid >> 6;
  const int lane = tid & 63;
  const int quad = lane >> 4;
  const int l16 = lane & 15;

  f16x8 qfrag = {};
  if (quad < 2) {
    const _Float16* qp =
        QKV + (size_t)(b * LL + q0 + w * 16 + l16) * RQKV + h * FD + quad * 8;
    qfrag = *(const f16x8*)qp;
  }

  f32x4 oacc[4];
#pragma unroll
  for (int nt = 0; nt < 4; nt++) oacc[nt] = (f32x4){0.f, 0.f, 0.f, 0.f};
  float zpart[4] = {0.f, 0.f, 0.f, 0.f};

  _Float16* sS2w = sS2 + w * 16 * SS_STRIDE;
  const int gq_base = q0 + w * 16;

  const int ktiles = blockIdx.x + 1;
  for (int kt = 0; kt < ktiles; kt++) {
    const int k0 = kt * 64;
    __syncthreads();
    {
      int key = tid >> 2, fg = (tid & 3) * 4;
      const _Float16* kp =
          QKV + (size_t)(b * LL + k0 + key) * RQKV + 256 + h * FD + fg;
      *(uint2*)&sK[key * SK_STRIDE + fg] = *(const uint2*)kp;
    }
    {
      int key = tid >> 2, c0 = (tid & 3) * 16;
      const _Float16* vp =
          QKV + (size_t)(b * LL + k0 + key) * RQKV + 512 + h * HD + c0;
      _Float16 tmp[16];
      *(f16x8*)&tmp[0] = *(const f16x8*)vp;
      *(f16x8*)&tmp[8] = *(const f16x8*)(vp + 8);
#pragma unroll
      for (int i = 0; i < 16; i++) sVt[(c0 + i) * SV_STRIDE + key] = tmp[i];
    }
    __syncthreads();

    f16x8 kf[4];
#pragma unroll
    for (int nt = 0; nt < 4; nt++) {
      f16x8 f = {};
      if (quad < 2) f = *(const f16x8*)&sK[(nt * 16 + l16) * SK_STRIDE + quad * 8];
      kf[nt] = f;
    }

#pragma unroll
    for (int nt = 0; nt < 4; nt++) {
      f32x4 s = __builtin_amdgcn_mfma_f32_16x16x32_f16(
          qfrag, kf[nt], (f32x4){0.f, 0.f, 0.f, 0.f}, 0, 0, 0);
      const int gk = k0 + nt * 16 + l16;
#pragma unroll
      for (int r = 0; r < 4; r++) {
        float sv = s[r] * 0.0625f;
        sv = sv * sv * S2SCALE;
        const int gq = gq_base + quad * 4 + r;
        sv = (gk <= gq) ? sv : 0.0f;
        zpart[r] += sv;
        sS2w[(quad * 4 + r) * SS_STRIDE + nt * 16 + l16] = (_Float16)sv;
      }
    }
    __asm__ volatile("s_waitcnt lgkmcnt(0)" ::: "memory");

    f16x8 af0 = *(const f16x8*)&sS2w[l16 * SS_STRIDE + quad * 8];
    f16x8 af1 = *(const f16x8*)&sS2w[l16 * SS_STRIDE + 32 + quad * 8];

#pragma unroll
    for (int nt = 0; nt < 4; nt++) {
      f16x8 vf0 = *(const f16x8*)&sVt[(nt * 16 + l16) * SV_STRIDE + quad * 8];
      f16x8 vf1 = *(const f16x8*)&sVt[(nt * 16 + l16) * SV_STRIDE + 32 + quad * 8];
      oacc[nt] = __builtin_amdgcn_mfma_f32_16x16x32_f16(af0, vf0, oacc[nt], 0, 0, 0);
      oacc[nt] = __builtin_amdgcn_mfma_f32_16x16x32_f16(af1, vf1, oacc[nt], 0, 0, 0);
    }
  }

  float rz[4];
#pragma unroll
  for (int r = 0; r < 4; r++) {
    float t = zpart[r];
    t += __shfl_xor(t, 1);
    t += __shfl_xor(t, 2);
    t += __shfl_xor(t, 4);
    t += __shfl_xor(t, 8);
    rz[r] = 1.0f / (t + S2SCALE * EPS);
  }
#pragma unroll
  for (int nt = 0; nt < 4; nt++) {
#pragma unroll
    for (int r = 0; r < 4; r++) {
      const int gq = gq_base + quad * 4 + r;
      O[(size_t)(b * LL + gq) * (HH * HD) + h * HD + nt * 16 + l16] =
          (_Float16)(oacc[nt][r] * rz[r]);
    }
  }
}

// ---------------------------------------------------------------------------
// early_qkv: QKVe[8][1536] = hs_early[8][1024] @ [Wq|Wk|Wv], ALL fp32.
// (Early rows must come from fp32 inputs: fp16-sourced q,k give |ds|~4e-4,
// which the s^2/(z+eps) ratio amplifies to ~0.1 output error on low-z rows.)
// Grid 48 blocks: block bx owns output cols bx*32..+31 (col tiles never
// straddle the Wq/Wk/Wv boundaries at 256/512). 256 thr = 8 kgroups x 32 cols.
// Each thread: 8 row-accumulators over its 128-k slice, branch-free, W reads
// coalesced (32 consecutive cols/wave-half per k). LDS kgroup-reduce at end.
// ---------------------------------------------------------------------------
__global__ __launch_bounds__(256) void early_qkv(
    const float* __restrict__ hs, const float* __restrict__ Wq,
    const float* __restrict__ Wk, const float* __restrict__ Wv,
    float* __restrict__ QKVe) {
  __shared__ float sHS[8][DD];          // 32 KB
  __shared__ float part[8][8][32];      // [kg][row][col] 8 KB
  const int tid = threadIdx.x;
  const int kg = tid >> 5, c = tid & 31;
  const int c0 = blockIdx.x * 32;

  // stage the 8 early hs rows (b in {0,1} x r in {0..3})
  for (int i = tid; i < 8 * (DD / 4); i += 256) {
    int e = i / (DD / 4), col4 = (i % (DD / 4)) * 4;
    int b = e >> 2, r = e & 3;
    *(float4*)&sHS[e][col4] =
        *(const float4*)(hs + (size_t)(b * LL + r) * DD + col4);
  }
  __syncthreads();

  // pick weight matrix + local column
  const float* W;
  int col, ncol;
  if (c0 < 256) { W = Wq; col = c0 + c; ncol = 256; }
  else if (c0 < 512) { W = Wk; col = (c0 - 256) + c; ncol = 256; }
  else { W = Wv; col = (c0 - 512) + c; ncol = 1024; }

  float acc[8] = {};
  const int d0 = kg * 128;
#pragma unroll 4
  for (int d = d0; d < d0 + 128; d++) {
    float wv = W[(size_t)d * ncol + col];
#pragma unroll
    for (int e = 0; e < 8; e++) acc[e] += sHS[e][d] * wv;
  }
#pragma unroll
  for (int e = 0; e < 8; e++) part[kg][e][c] = acc[e];
  __syncthreads();

  // reduce kgroups: one thread per (e, c) output
  {
    int e = tid >> 5;  // 0..7
    float t = 0.f;
#pragma unroll
    for (int g = 0; g < 8; g++) t += part[g][e][c];
    QKVe[(size_t)e * RQKV + c0 + c] = t;
  }
}

// ---------------------------------------------------------------------------
// fix_final: exact fp32 ratio for the first NFIX positions per (b,h), reading
// the fp32 QKVe buffer. Grid 32 = (b,h); 256 thr = (p, d). Trivial cost.
// ---------------------------------------------------------------------------
__global__ __launch_bounds__(256) void fix_final(
    const float* __restrict__ QKVe, _Float16* __restrict__ Oatt) {
  const int b = blockIdx.x >> 4, h = blockIdx.x & 15;
  const int tid = threadIdx.x;
  const int p = tid >> 6, d = tid & 63;

  float num = 0.f, z = 0.f;
  const float* qrow = QKVe + (size_t)(b * 4 + p) * RQKV + h * FD;
  for (int j = 0; j <= p; j++) {
    const float* krow = QKVe + (size_t)(b * 4 + j) * RQKV + 256 + h * FD;
    float s = 0.f;
#pragma unroll
    for (int f = 0; f < FD; f++) s += qrow[f] * krow[f];
    s *= 0.25f;  // FD^-0.5
    s = s * s;
    z += s;
    num += s * QKVe[(size_t)(b * 4 + j) * RQKV + 512 + h * HD + d];
  }
  Oatt[(size_t)(b * LL + p) * (HH * HD) + h * HD + d] =
      (_Float16)(num / (z + EPS));
}

// ---------------------------------------------------------------------------
// Launch
// ---------------------------------------------------------------------------
extern "C" void kernel_launch(void* const* d_in, const int* in_sizes, int n_in,
                              void* d_out, int out_size, void* d_ws, size_t ws_size,
                              hipStream_t stream) {
  const float* hs = (const float*)d_in[0];  // [4096, 1024]
  const float* Wq = (const float*)d_in[1];  // [1024, 256]
  const float* Wk = (const float*)d_in[2];  // [1024, 256]
  const float* Wv = (const float*)d_in[3];  // [1024, 1024]
  const float* Wo = (const float*)d_in[4];  // [1024, 1024]
  float* out = (float*)d_out;               // [4096, 1024]

  char* ws = (char*)d_ws;
  _Float16* WqkvT = (_Float16*)ws;                    // [1536][1024] = 3 MiB
  _Float16* WoT   = (_Float16*)(ws + (3ull << 20));   // [1024][1024] = 2 MiB
  _Float16* QKV   = (_Float16*)(ws + (8ull << 20));   // [4096][1536] = 12 MiB
  _Float16* Oatt  = (_Float16*)(ws + (20ull << 20));  // [4096][1024] = 8 MiB
  float*    QKVe  = (float*)(ws + (28ull << 20));     // [8][1536] fp32 = 48 KiB

  const int M = BB * LL;  // 4096

  transpose_cast<<<dim3(256 / 32, DD / 32), 256, 0, stream>>>(Wq, WqkvT, DD, 256);
  transpose_cast<<<dim3(256 / 32, DD / 32), 256, 0, stream>>>(Wk, WqkvT + 256 * DD, DD, 256);
  transpose_cast<<<dim3(DD / 32, DD / 32), 256, 0, stream>>>(Wv, WqkvT + 512 * DD, DD, DD);
  transpose_cast<<<dim3(DD / 32, DD / 32), 256, 0, stream>>>(Wo, WoT, DD, DD);

  // fp32 projections for the 8 early rows (runs alongside the big GEMM's slot)
  early_qkv<<<dim3(RQKV / 32), 256, 0, stream>>>(hs, Wq, Wk, Wv, QKVe);

  gemm_tn<float, _Float16><<<dim3(RQKV / 128, M / 128), 256, 0, stream>>>(
      hs, WqkvT, QKV, M, RQKV, DD);

  attn_mfma<<<dim3(LL / 64, BB * HH), 256, 0, stream>>>(QKV, Oatt);

  // exact fp32 first-NFIX rows per (b,h), from the fp32 QKVe buffer
  fix_final<<<dim3(BB * HH), 256, 0, stream>>>(QKVe, Oatt);

  gemm_tn<_Float16, float><<<dim3(DD / 128, M / 128), 256, 0, stream>>>(
      Oatt, WoT, out, M, DD, DD);
}

// Round 8
// 233.136 us; speedup vs baseline: 2.5532x; 1.0437x over previous
//
#include <hip/hip_runtime.h>
#include <hip/hip_bf16.h>

// Problem constants
#define BB 2
#define LL 2048
#define DD 1024
#define HH 16
#define FD 16
#define HD 64
#define EPS 1e-5f
#define RQKV 1536   // fused QKV row stride (256 Q + 256 K + 1024 V)
#define NFIX 4      // first NFIX positions per (b,h) recomputed in fp32 (low-z rows)

typedef __attribute__((ext_vector_type(4))) float f32x4;
typedef __attribute__((ext_vector_type(8))) _Float16 f16x8;
typedef __attribute__((ext_vector_type(4))) _Float16 f16x4;

// ---------------------------------------------------------------------------
// Transpose + cast: src fp32 [K][N] -> dst fp16 [N][K]. Grid (N/32, K/32).
// ---------------------------------------------------------------------------
__global__ __launch_bounds__(256) void transpose_cast(
    const float* __restrict__ src, _Float16* __restrict__ dst, int K, int N) {
  __shared__ _Float16 s[32][40];
  const int n0 = blockIdx.x * 32, k0 = blockIdx.y * 32;
  const int tid = threadIdx.x;
  {
    int r = tid >> 3, c = (tid & 7) * 4;
    float4 v = *(const float4*)(src + (size_t)(k0 + r) * N + n0 + c);
    f16x4 p = {(_Float16)v.x, (_Float16)v.y, (_Float16)v.z, (_Float16)v.w};
    *(f16x4*)&s[r][c] = p;
  }
  __syncthreads();
  {
    int n = tid >> 3, kk = (tid & 7) * 4;
    f16x4 o = {s[kk + 0][n], s[kk + 1][n], s[kk + 2][n], s[kk + 3][n]};
    *(f16x4*)(dst + (size_t)(n0 + n) * K + k0 + kk) = o;
  }
}

// ---------------------------------------------------------------------------
// MFMA GEMM: C[M,N] = A[M,K] @ Bt[N,K]^T. 128x128 tile, BK=32, 4 waves.
// ---------------------------------------------------------------------------
template <typename AT, typename OutT>
__global__ __launch_bounds__(256) void gemm_tn(
    const AT* __restrict__ A, const _Float16* __restrict__ Bt,
    OutT* __restrict__ C, int M, int N, int K) {
  constexpr int LDT = 40;
  __shared__ __attribute__((aligned(16))) _Float16 sA[128 * LDT];
  __shared__ __attribute__((aligned(16))) _Float16 sB[128 * LDT];
  const int tid = threadIdx.x;
  const int m0 = blockIdx.y * 128, n0 = blockIdx.x * 128;
  const int w = tid >> 6, lane = tid & 63, quad = lane >> 4, l16 = lane & 15;
  const int wm = (w >> 1) * 64, wn = (w & 1) * 64;

  const int sr = tid >> 1, sh = (tid & 1) * 16;
  const AT* Ag = A + (size_t)(m0 + sr) * K + sh;
  const _Float16* Bg = Bt + (size_t)(n0 + sr) * K + sh;
  _Float16* sAw = &sA[sr * LDT + sh];
  _Float16* sBw = &sB[sr * LDT + sh];

  f32x4 acc[4][4];
#pragma unroll
  for (int i = 0; i < 4; i++)
#pragma unroll
    for (int j = 0; j < 4; j++) acc[i][j] = (f32x4){0.f, 0.f, 0.f, 0.f};

  for (int k0 = 0; k0 < K; k0 += 32) {
    __syncthreads();
    if constexpr (sizeof(AT) == 4) {
      float4 a0 = *(const float4*)(Ag + k0);
      float4 a1 = *(const float4*)(Ag + k0 + 4);
      float4 a2 = *(const float4*)(Ag + k0 + 8);
      float4 a3 = *(const float4*)(Ag + k0 + 12);
      f16x8 p0 = {(_Float16)a0.x, (_Float16)a0.y, (_Float16)a0.z, (_Float16)a0.w,
                  (_Float16)a1.x, (_Float16)a1.y, (_Float16)a1.z, (_Float16)a1.w};
      f16x8 p1 = {(_Float16)a2.x, (_Float16)a2.y, (_Float16)a2.z, (_Float16)a2.w,
                  (_Float16)a3.x, (_Float16)a3.y, (_Float16)a3.z, (_Float16)a3.w};
      *(f16x8*)sAw = p0;
      *(f16x8*)(sAw + 8) = p1;
    } else {
      *(f16x8*)sAw = *(const f16x8*)(Ag + k0);
      *(f16x8*)(sAw + 8) = *(const f16x8*)(Ag + k0 + 8);
    }
    *(f16x8*)sBw = *(const f16x8*)(Bg + k0);
    *(f16x8*)(sBw + 8) = *(const f16x8*)(Bg + k0 + 8);
    __syncthreads();

    f16x8 af[4], bf[4];
#pragma unroll
    for (int i = 0; i < 4; i++)
      af[i] = *(const f16x8*)&sA[(wm + i * 16 + l16) * LDT + quad * 8];
#pragma unroll
    for (int j = 0; j < 4; j++)
      bf[j] = *(const f16x8*)&sB[(wn + j * 16 + l16) * LDT + quad * 8];
#pragma unroll
    for (int i = 0; i < 4; i++)
#pragma unroll
      for (int j = 0; j < 4; j++)
        acc[i][j] = __builtin_amdgcn_mfma_f32_16x16x32_f16(af[i], bf[j], acc[i][j], 0, 0, 0);
  }

#pragma unroll
  for (int i = 0; i < 4; i++)
#pragma unroll
    for (int j = 0; j < 4; j++)
#pragma unroll
      for (int r = 0; r < 4; r++) {
        const int row = m0 + wm + i * 16 + quad * 4 + r;
        const int col = n0 + wn + j * 16 + l16;
        C[(size_t)row * N + col] = (OutT)acc[i][j][r];
      }
}

// ---------------------------------------------------------------------------
// MFMA causal quadratic attention, v2.
// 128 queries/block (wave w owns 32: two 16-row m-tiles), 64-key tiles.
// Stored S2 = 2*(q.k)^2  (== old /16-scale * 512: exact same encoding);
// o = num/(z + 32*EPS) compensates.  z computed via MFMA against a ones-row
// tile appended to sVt (rows 64..79: row 64 = ones, 65..79 = zeros).
// V staged transposed conflict-free: wave w writes hd rows w*16..+15 with
// lane=key (each ds_write covers 64 consecutive ushorts).
// Masking (cndmask) only on boundary k-tiles; fully-masked tiles skipped.
// ---------------------------------------------------------------------------
#define SK2 24   // sK stride (ushorts)
#define SV2 72   // sVt stride
#define SS2 72   // sS2 stride

__global__ __launch_bounds__(256) void attn_mfma2(
    const _Float16* __restrict__ QKV, _Float16* __restrict__ O) {
  __shared__ __attribute__((aligned(16))) _Float16 sK[64 * SK2];    // 3 KB
  __shared__ __attribute__((aligned(16))) _Float16 sVt[80 * SV2];   // 11.25 KB
  __shared__ __attribute__((aligned(16))) _Float16 sS2[4 * 32 * SS2]; // 18 KB

  const int bh = blockIdx.y;
  const int b = bh >> 4, h = bh & 15;
  const int qt = (int)gridDim.x - 1 - (int)blockIdx.x;  // big blocks first
  const int q0 = qt * 128;
  const int tid = threadIdx.x;
  const int w = tid >> 6;
  const int lane = tid & 63;
  const int quad = lane >> 4;
  const int l16 = lane & 15;
  const int gqw = q0 + w * 32;

  // Q A-frags (k>=16 zero-padded)
  f16x8 qfrag[2] = {{}, {}};
  if (quad < 2) {
#pragma unroll
    for (int m = 0; m < 2; m++)
      qfrag[m] = *(const f16x8*)(QKV +
          (size_t)(b * LL + gqw + m * 16 + l16) * RQKV + h * FD + quad * 8);
  }

  // z-ones tile: sVt rows 64..79 (row 64 = ones for keys 0..63, rest zero)
  for (int i = tid; i < 16 * SV2; i += 256) {
    int r = i / SV2, c = i % SV2;
    sVt[64 * SV2 + i] = (_Float16)((r == 0 && c < 64) ? 1.0f : 0.0f);
  }
  __syncthreads();
  const f16x8 zf0 = *(const f16x8*)&sVt[(64 + l16) * SV2 + quad * 8];
  const f16x8 zf1 = *(const f16x8*)&sVt[(64 + l16) * SV2 + 32 + quad * 8];

  f32x4 oacc[2][4];
  f32x4 zacc[2];
#pragma unroll
  for (int m = 0; m < 2; m++) {
    zacc[m] = (f32x4){0.f, 0.f, 0.f, 0.f};
#pragma unroll
    for (int nt = 0; nt < 4; nt++) oacc[m][nt] = (f32x4){0.f, 0.f, 0.f, 0.f};
  }

  _Float16* sS2w = sS2 + w * 32 * SS2;
  const int ktiles = 2 * qt + 2;

  for (int kt = 0; kt < ktiles; kt++) {
    const int k0 = kt * 64;
    __syncthreads();
    // stage K tile (64 keys x 16 f, 8B/thread)
    {
      int key = tid >> 2, fg = (tid & 3) * 4;
      *(uint2*)&sK[key * SK2 + fg] = *(const uint2*)(QKV +
          (size_t)(b * LL + k0 + key) * RQKV + 256 + h * FD + fg);
    }
    // stage V transposed, conflict-free: wave w -> hd rows w*16..+15, lane=key
    {
      const _Float16* vp = QKV +
          (size_t)(b * LL + k0 + lane) * RQKV + 512 + h * HD + w * 16;
      f16x8 t0 = *(const f16x8*)vp;
      f16x8 t1 = *(const f16x8*)(vp + 8);
#pragma unroll
      for (int i = 0; i < 8; i++) sVt[(w * 16 + i) * SV2 + lane] = t0[i];
#pragma unroll
      for (int i = 0; i < 8; i++) sVt[(w * 16 + 8 + i) * SV2 + lane] = t1[i];
    }
    __syncthreads();

    if (k0 > gqw + 31) continue;          // fully masked for this wave
    const bool need_mask = (k0 + 63 > gqw);

    // S = Q K^T ; store sv = 2*s^2 (masked on boundary tiles only)
#pragma unroll
    for (int nt = 0; nt < 4; nt++) {
      f16x8 kf = {};
      if (quad < 2) kf = *(const f16x8*)&sK[(nt * 16 + l16) * SK2 + quad * 8];
#pragma unroll
      for (int m = 0; m < 2; m++) {
        f32x4 s = __builtin_amdgcn_mfma_f32_16x16x32_f16(
            qfrag[m], kf, (f32x4){0.f, 0.f, 0.f, 0.f}, 0, 0, 0);
        if (need_mask) {
          const int gk = k0 + nt * 16 + l16;
#pragma unroll
          for (int r = 0; r < 4; r++) {
            float sv = s[r] * s[r] * 2.0f;
            const int gq = gqw + m * 16 + quad * 4 + r;
            sv = (gk <= gq) ? sv : 0.0f;
            sS2w[(m * 16 + quad * 4 + r) * SS2 + nt * 16 + l16] = (_Float16)sv;
          }
        } else {
#pragma unroll
          for (int r = 0; r < 4; r++) {
            float sv = s[r] * s[r] * 2.0f;
            sS2w[(m * 16 + quad * 4 + r) * SS2 + nt * 16 + l16] = (_Float16)sv;
          }
        }
      }
    }
    // wave-private LDS round trip: drain writes before frag reads
    __asm__ volatile("s_waitcnt lgkmcnt(0)" ::: "memory");

    f16x8 af0[2], af1[2];
#pragma unroll
    for (int m = 0; m < 2; m++) {
      af0[m] = *(const f16x8*)&sS2w[(m * 16 + l16) * SS2 + quad * 8];
      af1[m] = *(const f16x8*)&sS2w[(m * 16 + l16) * SS2 + 32 + quad * 8];
    }

    // O += S2 @ V ; z += S2 @ ones
#pragma unroll
    for (int nt = 0; nt < 4; nt++) {
      f16x8 vf0 = *(const f16x8*)&sVt[(nt * 16 + l16) * SV2 + quad * 8];
      f16x8 vf1 = *(const f16x8*)&sVt[(nt * 16 + l16) * SV2 + 32 + quad * 8];
#pragma unroll
      for (int m = 0; m < 2; m++) {
        oacc[m][nt] = __builtin_amdgcn_mfma_f32_16x16x32_f16(af0[m], vf0, oacc[m][nt], 0, 0, 0);
        oacc[m][nt] = __builtin_amdgcn_mfma_f32_16x16x32_f16(af1[m], vf1, oacc[m][nt], 0, 0, 0);
      }
    }
#pragma unroll
    for (int m = 0; m < 2; m++) {
      zacc[m] = __builtin_amdgcn_mfma_f32_16x16x32_f16(af0[m], zf0, zacc[m], 0, 0, 0);
      zacc[m] = __builtin_amdgcn_mfma_f32_16x16x32_f16(af1[m], zf1, zacc[m], 0, 0, 0);
    }
  }

  // epilogue: z lives in col 0 (lane quad*16); broadcast, invert, store
#pragma unroll
  for (int m = 0; m < 2; m++) {
    float rz[4];
#pragma unroll
    for (int r = 0; r < 4; r++) {
      float zz = __shfl(zacc[m][r], lane & 48);
      rz[r] = 1.0f / (zz + 32.0f * EPS);
    }
#pragma unroll
    for (int nt = 0; nt < 4; nt++) {
#pragma unroll
      for (int r = 0; r < 4; r++) {
        const int gq = gqw + m * 16 + quad * 4 + r;
        O[(size_t)(b * LL + gq) * (HH * HD) + h * HD + nt * 16 + l16] =
            (_Float16)(oacc[m][nt][r] * rz[r]);
      }
    }
  }
}

// ---------------------------------------------------------------------------
// early_qkv: QKVe[8][1536] = hs_early[8][1024] @ [Wq|Wk|Wv], ALL fp32.
// (Early rows must come from fp32 inputs: fp16-sourced q,k give |ds|~4e-4,
// which s^2/(z+eps) amplifies to ~0.1 output error on low-z rows.)
// ---------------------------------------------------------------------------
__global__ __launch_bounds__(256) void early_qkv(
    const float* __restrict__ hs, const float* __restrict__ Wq,
    const float* __restrict__ Wk, const float* __restrict__ Wv,
    float* __restrict__ QKVe) {
  __shared__ float sHS[8][DD];
  __shared__ float part[8][8][32];
  const int tid = threadIdx.x;
  const int kg = tid >> 5, c = tid & 31;
  const int c0 = blockIdx.x * 32;

  for (int i = tid; i < 8 * (DD / 4); i += 256) {
    int e = i / (DD / 4), col4 = (i % (DD / 4)) * 4;
    int b = e >> 2, r = e & 3;
    *(float4*)&sHS[e][col4] =
        *(const float4*)(hs + (size_t)(b * LL + r) * DD + col4);
  }
  __syncthreads();

  const float* W;
  int col, ncol;
  if (c0 < 256) { W = Wq; col = c0 + c; ncol = 256; }
  else if (c0 < 512) { W = Wk; col = (c0 - 256) + c; ncol = 256; }
  else { W = Wv; col = (c0 - 512) + c; ncol = 1024; }

  float acc[8] = {};
  const int d0 = kg * 128;
#pragma unroll 4
  for (int d = d0; d < d0 + 128; d++) {
    float wv = W[(size_t)d * ncol + col];
#pragma unroll
    for (int e = 0; e < 8; e++) acc[e] += sHS[e][d] * wv;
  }
#pragma unroll
  for (int e = 0; e < 8; e++) part[kg][e][c] = acc[e];
  __syncthreads();

  {
    int e = tid >> 5;
    float t = 0.f;
#pragma unroll
    for (int g = 0; g < 8; g++) t += part[g][e][c];
    QKVe[(size_t)e * RQKV + c0 + c] = t;
  }
}

// ---------------------------------------------------------------------------
// fix_final: exact fp32 ratio for the first NFIX positions per (b,h).
// ---------------------------------------------------------------------------
__global__ __launch_bounds__(256) void fix_final(
    const float* __restrict__ QKVe, _Float16* __restrict__ Oatt) {
  const int b = blockIdx.x >> 4, h = blockIdx.x & 15;
  const int tid = threadIdx.x;
  const int p = tid >> 6, d = tid & 63;

  float num = 0.f, z = 0.f;
  const float* qrow = QKVe + (size_t)(b * 4 + p) * RQKV + h * FD;
  for (int j = 0; j <= p; j++) {
    const float* krow = QKVe + (size_t)(b * 4 + j) * RQKV + 256 + h * FD;
    float s = 0.f;
#pragma unroll
    for (int f = 0; f < FD; f++) s += qrow[f] * krow[f];
    s *= 0.25f;
    s = s * s;
    z += s;
    num += s * QKVe[(size_t)(b * 4 + j) * RQKV + 512 + h * HD + d];
  }
  Oatt[(size_t)(b * LL + p) * (HH * HD) + h * HD + d] =
      (_Float16)(num / (z + EPS));
}

// ---------------------------------------------------------------------------
// Launch
// ---------------------------------------------------------------------------
extern "C" void kernel_launch(void* const* d_in, const int* in_sizes, int n_in,
                              void* d_out, int out_size, void* d_ws, size_t ws_size,
                              hipStream_t stream) {
  const float* hs = (const float*)d_in[0];  // [4096, 1024]
  const float* Wq = (const float*)d_in[1];  // [1024, 256]
  const float* Wk = (const float*)d_in[2];  // [1024, 256]
  const float* Wv = (const float*)d_in[3];  // [1024, 1024]
  const float* Wo = (const float*)d_in[4];  // [1024, 1024]
  float* out = (float*)d_out;               // [4096, 1024]

  char* ws = (char*)d_ws;
  _Float16* WqkvT = (_Float16*)ws;                    // [1536][1024] = 3 MiB
  _Float16* WoT   = (_Float16*)(ws + (3ull << 20));   // [1024][1024] = 2 MiB
  _Float16* QKV   = (_Float16*)(ws + (8ull << 20));   // [4096][1536] = 12 MiB
  _Float16* Oatt  = (_Float16*)(ws + (20ull << 20));  // [4096][1024] = 8 MiB
  float*    QKVe  = (float*)(ws + (28ull << 20));     // [8][1536] fp32

  const int M = BB * LL;  // 4096

  transpose_cast<<<dim3(256 / 32, DD / 32), 256, 0, stream>>>(Wq, WqkvT, DD, 256);
  transpose_cast<<<dim3(256 / 32, DD / 32), 256, 0, stream>>>(Wk, WqkvT + 256 * DD, DD, 256);
  transpose_cast<<<dim3(DD / 32, DD / 32), 256, 0, stream>>>(Wv, WqkvT + 512 * DD, DD, DD);
  transpose_cast<<<dim3(DD / 32, DD / 32), 256, 0, stream>>>(Wo, WoT, DD, DD);

  early_qkv<<<dim3(RQKV / 32), 256, 0, stream>>>(hs, Wq, Wk, Wv, QKVe);

  gemm_tn<float, _Float16><<<dim3(RQKV / 128, M / 128), 256, 0, stream>>>(
      hs, WqkvT, QKV, M, RQKV, DD);

  attn_mfma2<<<dim3(LL / 128, BB * HH), 256, 0, stream>>>(QKV, Oatt);

  fix_final<<<dim3(BB * HH), 256, 0, stream>>>(QKVe, Oatt);

  gemm_tn<_Float16, float><<<dim3(DD / 128, M / 128), 256, 0, stream>>>(
      Oatt, WoT, out, M, DD, DD);
}

// Round 9
// 210.804 us; speedup vs baseline: 2.8237x; 1.1059x over previous
//
#include <hip/hip_runtime.h>
#include <hip/hip_bf16.h>

// Problem constants
#define BB 2
#define LL 2048
#define DD 1024
#define HH 16
#define FD 16
#define HD 64
#define EPS 1e-5f
#define RQKV 1536   // fused QKV row stride (256 Q + 256 K + 1024 V)
#define NFIX 4      // first NFIX positions per (b,h) recomputed in fp32 (low-z rows)

typedef __attribute__((ext_vector_type(4))) float f32x4;
typedef __attribute__((ext_vector_type(8))) _Float16 f16x8;
typedef __attribute__((ext_vector_type(4))) _Float16 f16x4;

// ---------------------------------------------------------------------------
// Transpose + cast: src fp32 [K][N] -> dst fp16 [N][K]. Grid (N/32, K/32).
// ---------------------------------------------------------------------------
__global__ __launch_bounds__(256) void transpose_cast(
    const float* __restrict__ src, _Float16* __restrict__ dst, int K, int N) {
  __shared__ _Float16 s[32][40];
  const int n0 = blockIdx.x * 32, k0 = blockIdx.y * 32;
  const int tid = threadIdx.x;
  {
    int r = tid >> 3, c = (tid & 7) * 4;
    float4 v = *(const float4*)(src + (size_t)(k0 + r) * N + n0 + c);
    f16x4 p = {(_Float16)v.x, (_Float16)v.y, (_Float16)v.z, (_Float16)v.w};
    *(f16x4*)&s[r][c] = p;
  }
  __syncthreads();
  {
    int n = tid >> 3, kk = (tid & 7) * 4;
    f16x4 o = {s[kk + 0][n], s[kk + 1][n], s[kk + 2][n], s[kk + 3][n]};
    *(f16x4*)(dst + (size_t)(n0 + n) * K + k0 + kk) = o;
  }
}

// ---------------------------------------------------------------------------
// MFMA GEMM: C[M,N] = A[M,K] @ Bt[N,K]^T. 128x128 tile, BK=32, 4 waves.
// Register-prefetch of the next K-step's A/B overlaps global latency with MFMA.
// ---------------------------------------------------------------------------
template <typename AT, typename OutT>
__global__ __launch_bounds__(256) void gemm_tn(
    const AT* __restrict__ A, const _Float16* __restrict__ Bt,
    OutT* __restrict__ C, int M, int N, int K) {
  constexpr int LDT = 40;
  __shared__ __attribute__((aligned(16))) _Float16 sA[128 * LDT];
  __shared__ __attribute__((aligned(16))) _Float16 sB[128 * LDT];
  const int tid = threadIdx.x;
  const int m0 = blockIdx.y * 128, n0 = blockIdx.x * 128;
  const int w = tid >> 6, lane = tid & 63, quad = lane >> 4, l16 = lane & 15;
  const int wm = (w >> 1) * 64, wn = (w & 1) * 64;

  const int sr = tid >> 1, sh = (tid & 1) * 16;
  const AT* Ag = A + (size_t)(m0 + sr) * K + sh;
  const _Float16* Bg = Bt + (size_t)(n0 + sr) * K + sh;
  _Float16* sAw = &sA[sr * LDT + sh];
  _Float16* sBw = &sB[sr * LDT + sh];

  f32x4 acc[4][4];
#pragma unroll
  for (int i = 0; i < 4; i++)
#pragma unroll
    for (int j = 0; j < 4; j++) acc[i][j] = (f32x4){0.f, 0.f, 0.f, 0.f};

  float4 ar32[4];
  f16x8 ar16[2];
  f16x8 br[2];
  auto LOAD = [&](int k0) {
    if constexpr (sizeof(AT) == 4) {
      ar32[0] = *(const float4*)(Ag + k0);
      ar32[1] = *(const float4*)(Ag + k0 + 4);
      ar32[2] = *(const float4*)(Ag + k0 + 8);
      ar32[3] = *(const float4*)(Ag + k0 + 12);
    } else {
      ar16[0] = *(const f16x8*)(Ag + k0);
      ar16[1] = *(const f16x8*)(Ag + k0 + 8);
    }
    br[0] = *(const f16x8*)(Bg + k0);
    br[1] = *(const f16x8*)(Bg + k0 + 8);
  };
  LOAD(0);

  for (int k0 = 0; k0 < K; k0 += 32) {
    __syncthreads();
    if constexpr (sizeof(AT) == 4) {
      f16x8 p0 = {(_Float16)ar32[0].x, (_Float16)ar32[0].y, (_Float16)ar32[0].z, (_Float16)ar32[0].w,
                  (_Float16)ar32[1].x, (_Float16)ar32[1].y, (_Float16)ar32[1].z, (_Float16)ar32[1].w};
      f16x8 p1 = {(_Float16)ar32[2].x, (_Float16)ar32[2].y, (_Float16)ar32[2].z, (_Float16)ar32[2].w,
                  (_Float16)ar32[3].x, (_Float16)ar32[3].y, (_Float16)ar32[3].z, (_Float16)ar32[3].w};
      *(f16x8*)sAw = p0;
      *(f16x8*)(sAw + 8) = p1;
    } else {
      *(f16x8*)sAw = ar16[0];
      *(f16x8*)(sAw + 8) = ar16[1];
    }
    *(f16x8*)sBw = br[0];
    *(f16x8*)(sBw + 8) = br[1];
    __syncthreads();
    if (k0 + 32 < K) LOAD(k0 + 32);  // prefetch overlaps the MFMAs below

    f16x8 af[4], bf[4];
#pragma unroll
    for (int i = 0; i < 4; i++)
      af[i] = *(const f16x8*)&sA[(wm + i * 16 + l16) * LDT + quad * 8];
#pragma unroll
    for (int j = 0; j < 4; j++)
      bf[j] = *(const f16x8*)&sB[(wn + j * 16 + l16) * LDT + quad * 8];
#pragma unroll
    for (int i = 0; i < 4; i++)
#pragma unroll
      for (int j = 0; j < 4; j++)
        acc[i][j] = __builtin_amdgcn_mfma_f32_16x16x32_f16(af[i], bf[j], acc[i][j], 0, 0, 0);
  }

#pragma unroll
  for (int i = 0; i < 4; i++)
#pragma unroll
    for (int j = 0; j < 4; j++)
#pragma unroll
      for (int r = 0; r < 4; r++) {
        const int row = m0 + wm + i * 16 + quad * 4 + r;
        const int col = n0 + wn + j * 16 + l16;
        C[(size_t)row * N + col] = (OutT)acc[i][j][r];
      }
}

// ---------------------------------------------------------------------------
// MFMA causal quadratic attention, v3.
// 64 queries/block (wave w owns 16), 64-key tiles, 1024 blocks -> 5/CU (LDS).
// Stored S2 = 2*(q.k)^2; o = num/(z + 32*EPS). z via MFMA against a ones-row
// tile (sVt rows 64..79). Register prefetch of next K/V tile overlaps global
// latency with compute. Strides 88 (176B, 16B-aligned, 44 dwords == 12 mod 32)
// give ~2-way (free) banking on all b128 fragment reads.
// Only the LAST ktile needs causal masking (k0 = q0, queries q0+16w..+15).
// ---------------------------------------------------------------------------
#define SK3 24   // sK stride (ushorts)
#define SV3 88   // sVt stride
#define SS3 88   // sS2 stride

__global__ __launch_bounds__(256) void attn_mfma3(
    const _Float16* __restrict__ QKV, _Float16* __restrict__ O) {
  __shared__ __attribute__((aligned(16))) _Float16 sK[64 * SK3];     // 3 KB
  __shared__ __attribute__((aligned(16))) _Float16 sVt[80 * SV3];    // 13.75 KB
  __shared__ __attribute__((aligned(16))) _Float16 sS2[4 * 16 * SS3]; // 11 KB

  const int bh = blockIdx.y;
  const int b = bh >> 4, h = bh & 15;
  const int qt = (int)gridDim.x - 1 - (int)blockIdx.x;  // big blocks first
  const int q0 = qt * 64;
  const int tid = threadIdx.x;
  const int w = tid >> 6;
  const int lane = tid & 63;
  const int quad = lane >> 4;
  const int l16 = lane & 15;
  const int gqw = q0 + w * 16;

  // Q A-frag (k>=16 zero-padded)
  f16x8 qfrag = {};
  if (quad < 2) {
    qfrag = *(const f16x8*)(QKV +
        (size_t)(b * LL + gqw + l16) * RQKV + h * FD + quad * 8);
  }

  // z-ones tile: sVt rows 64..79 (row 64 = ones for keys 0..63, rest zero)
  for (int i = tid; i < 16 * SV3; i += 256) {
    int r = i / SV3, c = i % SV3;
    sVt[64 * SV3 + i] = (_Float16)((r == 0 && c < 64) ? 1.0f : 0.0f);
  }
  __syncthreads();
  const f16x8 zf0 = *(const f16x8*)&sVt[(64 + l16) * SV3 + quad * 8];
  const f16x8 zf1 = *(const f16x8*)&sVt[(64 + l16) * SV3 + 32 + quad * 8];

  f32x4 oacc[4];
  f32x4 zacc = (f32x4){0.f, 0.f, 0.f, 0.f};
#pragma unroll
  for (int nt = 0; nt < 4; nt++) oacc[nt] = (f32x4){0.f, 0.f, 0.f, 0.f};

  _Float16* sS2w = sS2 + w * 16 * SS3;
  const int ktiles = qt + 1;

  // staging assignments + prefetch registers
  const int skey = tid >> 2, sfg = (tid & 3) * 4;
  uint2 kreg;
  f16x8 vreg0, vreg1;
  auto LOAD = [&](int kt) {
    kreg = *(const uint2*)(QKV +
        (size_t)(b * LL + kt * 64 + skey) * RQKV + 256 + h * FD + sfg);
    const _Float16* vp = QKV +
        (size_t)(b * LL + kt * 64 + lane) * RQKV + 512 + h * HD + w * 16;
    vreg0 = *(const f16x8*)vp;
    vreg1 = *(const f16x8*)(vp + 8);
  };
  LOAD(0);

  for (int kt = 0; kt < ktiles; kt++) {
    __syncthreads();  // previous iteration's LDS readers done
    *(uint2*)&sK[skey * SK3 + sfg] = kreg;
#pragma unroll
    for (int i = 0; i < 8; i++) sVt[(w * 16 + i) * SV3 + lane] = vreg0[i];
#pragma unroll
    for (int i = 0; i < 8; i++) sVt[(w * 16 + 8 + i) * SV3 + lane] = vreg1[i];
    __syncthreads();
    if (kt + 1 < ktiles) LOAD(kt + 1);  // prefetch overlaps compute below

    const bool need_mask = (kt == ktiles - 1);  // only k0 == q0 tile masks
    const int k0 = kt * 64;

    // S = Q K^T ; store sv = 2*s^2
#pragma unroll
    for (int nt = 0; nt < 4; nt++) {
      f16x8 kf = {};
      if (quad < 2) kf = *(const f16x8*)&sK[(nt * 16 + l16) * SK3 + quad * 8];
      f32x4 s = __builtin_amdgcn_mfma_f32_16x16x32_f16(
          qfrag, kf, (f32x4){0.f, 0.f, 0.f, 0.f}, 0, 0, 0);
      if (need_mask) {
        const int gk = k0 + nt * 16 + l16;
#pragma unroll
        for (int r = 0; r < 4; r++) {
          float sv = s[r] * s[r] * 2.0f;
          const int gq = gqw + quad * 4 + r;
          sv = (gk <= gq) ? sv : 0.0f;
          sS2w[(quad * 4 + r) * SS3 + nt * 16 + l16] = (_Float16)sv;
        }
      } else {
#pragma unroll
        for (int r = 0; r < 4; r++) {
          float sv = s[r] * s[r] * 2.0f;
          sS2w[(quad * 4 + r) * SS3 + nt * 16 + l16] = (_Float16)sv;
        }
      }
    }
    // wave-private LDS round trip: drain writes before frag reads
    __asm__ volatile("s_waitcnt lgkmcnt(0)" ::: "memory");

    f16x8 af0 = *(const f16x8*)&sS2w[l16 * SS3 + quad * 8];
    f16x8 af1 = *(const f16x8*)&sS2w[l16 * SS3 + 32 + quad * 8];

    // O += S2 @ V ; z += S2 @ ones
#pragma unroll
    for (int nt = 0; nt < 4; nt++) {
      f16x8 vf0 = *(const f16x8*)&sVt[(nt * 16 + l16) * SV3 + quad * 8];
      f16x8 vf1 = *(const f16x8*)&sVt[(nt * 16 + l16) * SV3 + 32 + quad * 8];
      oacc[nt] = __builtin_amdgcn_mfma_f32_16x16x32_f16(af0, vf0, oacc[nt], 0, 0, 0);
      oacc[nt] = __builtin_amdgcn_mfma_f32_16x16x32_f16(af1, vf1, oacc[nt], 0, 0, 0);
    }
    zacc = __builtin_amdgcn_mfma_f32_16x16x32_f16(af0, zf0, zacc, 0, 0, 0);
    zacc = __builtin_amdgcn_mfma_f32_16x16x32_f16(af1, zf1, zacc, 0, 0, 0);
  }

  // epilogue: z lives in col 0 (lane quad*16); broadcast, invert, store
  float rz[4];
#pragma unroll
  for (int r = 0; r < 4; r++) {
    float zz = __shfl(zacc[r], lane & 48);
    rz[r] = 1.0f / (zz + 32.0f * EPS);
  }
#pragma unroll
  for (int nt = 0; nt < 4; nt++) {
#pragma unroll
    for (int r = 0; r < 4; r++) {
      const int gq = gqw + quad * 4 + r;
      O[(size_t)(b * LL + gq) * (HH * HD) + h * HD + nt * 16 + l16] =
          (_Float16)(oacc[nt][r] * rz[r]);
    }
  }
}

// ---------------------------------------------------------------------------
// early_qkv: QKVe[8][1536] = hs_early[8][1024] @ [Wq|Wk|Wv], ALL fp32.
// (Early rows must come from fp32 inputs: fp16-sourced q,k give |ds|~4e-4,
// which s^2/(z+eps) amplifies to ~0.1 output error on low-z rows.)
// ---------------------------------------------------------------------------
__global__ __launch_bounds__(256) void early_qkv(
    const float* __restrict__ hs, const float* __restrict__ Wq,
    const float* __restrict__ Wk, const float* __restrict__ Wv,
    float* __restrict__ QKVe) {
  __shared__ float sHS[8][DD];
  __shared__ float part[8][8][32];
  const int tid = threadIdx.x;
  const int kg = tid >> 5, c = tid & 31;
  const int c0 = blockIdx.x * 32;

  for (int i = tid; i < 8 * (DD / 4); i += 256) {
    int e = i / (DD / 4), col4 = (i % (DD / 4)) * 4;
    int b = e >> 2, r = e & 3;
    *(float4*)&sHS[e][col4] =
        *(const float4*)(hs + (size_t)(b * LL + r) * DD + col4);
  }
  __syncthreads();

  const float* W;
  int col, ncol;
  if (c0 < 256) { W = Wq; col = c0 + c; ncol = 256; }
  else if (c0 < 512) { W = Wk; col = (c0 - 256) + c; ncol = 256; }
  else { W = Wv; col = (c0 - 512) + c; ncol = 1024; }

  float acc[8] = {};
  const int d0 = kg * 128;
#pragma unroll 4
  for (int d = d0; d < d0 + 128; d++) {
    float wv = W[(size_t)d * ncol + col];
#pragma unroll
    for (int e = 0; e < 8; e++) acc[e] += sHS[e][d] * wv;
  }
#pragma unroll
  for (int e = 0; e < 8; e++) part[kg][e][c] = acc[e];
  __syncthreads();

  {
    int e = tid >> 5;
    float t = 0.f;
#pragma unroll
    for (int g = 0; g < 8; g++) t += part[g][e][c];
    QKVe[(size_t)e * RQKV + c0 + c] = t;
  }
}

// ---------------------------------------------------------------------------
// fix_final: exact fp32 ratio for the first NFIX positions per (b,h).
// ---------------------------------------------------------------------------
__global__ __launch_bounds__(256) void fix_final(
    const float* __restrict__ QKVe, _Float16* __restrict__ Oatt) {
  const int b = blockIdx.x >> 4, h = blockIdx.x & 15;
  const int tid = threadIdx.x;
  const int p = tid >> 6, d = tid & 63;

  float num = 0.f, z = 0.f;
  const float* qrow = QKVe + (size_t)(b * 4 + p) * RQKV + h * FD;
  for (int j = 0; j <= p; j++) {
    const float* krow = QKVe + (size_t)(b * 4 + j) * RQKV + 256 + h * FD;
    float s = 0.f;
#pragma unroll
    for (int f = 0; f < FD; f++) s += qrow[f] * krow[f];
    s *= 0.25f;
    s = s * s;
    z += s;
    num += s * QKVe[(size_t)(b * 4 + j) * RQKV + 512 + h * HD + d];
  }
  Oatt[(size_t)(b * LL + p) * (HH * HD) + h * HD + d] =
      (_Float16)(num / (z + EPS));
}

// ---------------------------------------------------------------------------
// Launch
// ---------------------------------------------------------------------------
extern "C" void kernel_launch(void* const* d_in, const int* in_sizes, int n_in,
                              void* d_out, int out_size, void* d_ws, size_t ws_size,
                              hipStream_t stream) {
  const float* hs = (const float*)d_in[0];  // [4096, 1024]
  const float* Wq = (const float*)d_in[1];  // [1024, 256]
  const float* Wk = (const float*)d_in[2];  // [1024, 256]
  const float* Wv = (const float*)d_in[3];  // [1024, 1024]
  const float* Wo = (const float*)d_in[4];  // [1024, 1024]
  float* out = (float*)d_out;               // [4096, 1024]

  char* ws = (char*)d_ws;
  _Float16* WqkvT = (_Float16*)ws;                    // [1536][1024] = 3 MiB
  _Float16* WoT   = (_Float16*)(ws + (3ull << 20));   // [1024][1024] = 2 MiB
  _Float16* QKV   = (_Float16*)(ws + (8ull << 20));   // [4096][1536] = 12 MiB
  _Float16* Oatt  = (_Float16*)(ws + (20ull << 20));  // [4096][1024] = 8 MiB
  float*    QKVe  = (float*)(ws + (28ull << 20));     // [8][1536] fp32

  const int M = BB * LL;  // 4096

  transpose_cast<<<dim3(256 / 32, DD / 32), 256, 0, stream>>>(Wq, WqkvT, DD, 256);
  transpose_cast<<<dim3(256 / 32, DD / 32), 256, 0, stream>>>(Wk, WqkvT + 256 * DD, DD, 256);
  transpose_cast<<<dim3(DD / 32, DD / 32), 256, 0, stream>>>(Wv, WqkvT + 512 * DD, DD, DD);
  transpose_cast<<<dim3(DD / 32, DD / 32), 256, 0, stream>>>(Wo, WoT, DD, DD);

  early_qkv<<<dim3(RQKV / 32), 256, 0, stream>>>(hs, Wq, Wk, Wv, QKVe);

  gemm_tn<float, _Float16><<<dim3(RQKV / 128, M / 128), 256, 0, stream>>>(
      hs, WqkvT, QKV, M, RQKV, DD);

  attn_mfma3<<<dim3(LL / 64, BB * HH), 256, 0, stream>>>(QKV, Oatt);

  fix_final<<<dim3(BB * HH), 256, 0, stream>>>(QKVe, Oatt);

  gemm_tn<_Float16, float><<<dim3(DD / 128, M / 128), 256, 0, stream>>>(
      Oatt, WoT, out, M, DD, DD);
}

// Round 10
// 189.019 us; speedup vs baseline: 3.1492x; 1.1152x over previous
//
#include <hip/hip_runtime.h>
#include <hip/hip_bf16.h>

// Problem constants
#define BB 2
#define LL 2048
#define DD 1024
#define HH 16
#define FD 16
#define HD 64
#define EPS 1e-5f
#define RQKV 1536   // fused QKV row stride (256 Q + 256 K + 1024 V)
#define NFIX 4      // first NFIX positions per (b,h) recomputed in fp32 (low-z rows)

typedef __attribute__((ext_vector_type(4))) float f32x4;
typedef __attribute__((ext_vector_type(8))) _Float16 f16x8;
typedef __attribute__((ext_vector_type(4))) _Float16 f16x4;

// ---------------------------------------------------------------------------
// Transpose + cast: src fp32 [K][N] -> dst fp16 [N][K]. Grid (N/32, K/32).
// ---------------------------------------------------------------------------
__global__ __launch_bounds__(256) void transpose_cast(
    const float* __restrict__ src, _Float16* __restrict__ dst, int K, int N) {
  __shared__ _Float16 s[32][40];
  const int n0 = blockIdx.x * 32, k0 = blockIdx.y * 32;
  const int tid = threadIdx.x;
  {
    int r = tid >> 3, c = (tid & 7) * 4;
    float4 v = *(const float4*)(src + (size_t)(k0 + r) * N + n0 + c);
    f16x4 p = {(_Float16)v.x, (_Float16)v.y, (_Float16)v.z, (_Float16)v.w};
    *(f16x4*)&s[r][c] = p;
  }
  __syncthreads();
  {
    int n = tid >> 3, kk = (tid & 7) * 4;
    f16x4 o = {s[kk + 0][n], s[kk + 1][n], s[kk + 2][n], s[kk + 3][n]};
    *(f16x4*)(dst + (size_t)(n0 + n) * K + k0 + kk) = o;
  }
}

// ---------------------------------------------------------------------------
// MFMA GEMM: C[M,N] = A[M,K] @ Bt[N,K]^T. 128x128 tile, BK=32, 4 waves.
// Register-prefetch of the next K-step's A/B overlaps global latency with MFMA.
// ---------------------------------------------------------------------------
template <typename AT, typename OutT>
__global__ __launch_bounds__(256) void gemm_tn(
    const AT* __restrict__ A, const _Float16* __restrict__ Bt,
    OutT* __restrict__ C, int M, int N, int K) {
  constexpr int LDT = 40;
  __shared__ __attribute__((aligned(16))) _Float16 sA[128 * LDT];
  __shared__ __attribute__((aligned(16))) _Float16 sB[128 * LDT];
  const int tid = threadIdx.x;
  const int m0 = blockIdx.y * 128, n0 = blockIdx.x * 128;
  const int w = tid >> 6, lane = tid & 63, quad = lane >> 4, l16 = lane & 15;
  const int wm = (w >> 1) * 64, wn = (w & 1) * 64;

  const int sr = tid >> 1, sh = (tid & 1) * 16;
  const AT* Ag = A + (size_t)(m0 + sr) * K + sh;
  const _Float16* Bg = Bt + (size_t)(n0 + sr) * K + sh;
  _Float16* sAw = &sA[sr * LDT + sh];
  _Float16* sBw = &sB[sr * LDT + sh];

  f32x4 acc[4][4];
#pragma unroll
  for (int i = 0; i < 4; i++)
#pragma unroll
    for (int j = 0; j < 4; j++) acc[i][j] = (f32x4){0.f, 0.f, 0.f, 0.f};

  float4 ar32[4];
  f16x8 ar16[2];
  f16x8 br[2];
  auto LOAD = [&](int k0) {
    if constexpr (sizeof(AT) == 4) {
      ar32[0] = *(const float4*)(Ag + k0);
      ar32[1] = *(const float4*)(Ag + k0 + 4);
      ar32[2] = *(const float4*)(Ag + k0 + 8);
      ar32[3] = *(const float4*)(Ag + k0 + 12);
    } else {
      ar16[0] = *(const f16x8*)(Ag + k0);
      ar16[1] = *(const f16x8*)(Ag + k0 + 8);
    }
    br[0] = *(const f16x8*)(Bg + k0);
    br[1] = *(const f16x8*)(Bg + k0 + 8);
  };
  LOAD(0);

  for (int k0 = 0; k0 < K; k0 += 32) {
    __syncthreads();
    if constexpr (sizeof(AT) == 4) {
      f16x8 p0 = {(_Float16)ar32[0].x, (_Float16)ar32[0].y, (_Float16)ar32[0].z, (_Float16)ar32[0].w,
                  (_Float16)ar32[1].x, (_Float16)ar32[1].y, (_Float16)ar32[1].z, (_Float16)ar32[1].w};
      f16x8 p1 = {(_Float16)ar32[2].x, (_Float16)ar32[2].y, (_Float16)ar32[2].z, (_Float16)ar32[2].w,
                  (_Float16)ar32[3].x, (_Float16)ar32[3].y, (_Float16)ar32[3].z, (_Float16)ar32[3].w};
      *(f16x8*)sAw = p0;
      *(f16x8*)(sAw + 8) = p1;
    } else {
      *(f16x8*)sAw = ar16[0];
      *(f16x8*)(sAw + 8) = ar16[1];
    }
    *(f16x8*)sBw = br[0];
    *(f16x8*)(sBw + 8) = br[1];
    __syncthreads();
    if (k0 + 32 < K) LOAD(k0 + 32);  // prefetch overlaps the MFMAs below

    f16x8 af[4], bf[4];
#pragma unroll
    for (int i = 0; i < 4; i++)
      af[i] = *(const f16x8*)&sA[(wm + i * 16 + l16) * LDT + quad * 8];
#pragma unroll
    for (int j = 0; j < 4; j++)
      bf[j] = *(const f16x8*)&sB[(wn + j * 16 + l16) * LDT + quad * 8];
#pragma unroll
    for (int i = 0; i < 4; i++)
#pragma unroll
      for (int j = 0; j < 4; j++)
        acc[i][j] = __builtin_amdgcn_mfma_f32_16x16x32_f16(af[i], bf[j], acc[i][j], 0, 0, 0);
  }

#pragma unroll
  for (int i = 0; i < 4; i++)
#pragma unroll
    for (int j = 0; j < 4; j++)
#pragma unroll
      for (int r = 0; r < 4; r++) {
        const int row = m0 + wm + i * 16 + quad * 4 + r;
        const int col = n0 + wn + j * 16 + l16;
        C[(size_t)row * N + col] = (OutT)acc[i][j][r];
      }
}

// ---------------------------------------------------------------------------
// MFMA causal quadratic attention, v4: paired complementary query tiles.
// Block x = i (0..15) handles q-tiles A = i and B = 31-i. Every block does
// exactly (i+1) + (32-i) = 33 compute-units -> perfectly balanced grid of 512
// blocks (2/CU, occupancy flat). For kt <= i the staged K/V tile AND the
// kf/vf fragments are shared by both query tiles (staging amortized 26%,
// per-MFMA DS overhead -30%).
// Stored S2 = 2*(q.k)^2; o = num/(z + 32*EPS). z via MFMA against ones-row
// tile (sVt rows 64..79). Register prefetch of next K/V tile. Strides 88.
// Masking only on each half's boundary tile (kt == qtX).
// ---------------------------------------------------------------------------
#define SK4 24   // sK stride (ushorts)
#define SV4 88   // sVt stride
#define SS4 88   // sS2 stride

__global__ __launch_bounds__(256) void attn_mfma4(
    const _Float16* __restrict__ QKV, _Float16* __restrict__ O) {
  __shared__ __attribute__((aligned(16))) _Float16 sK[64 * SK4];      // 3 KB
  __shared__ __attribute__((aligned(16))) _Float16 sVt[80 * SV4];     // 13.75 KB
  __shared__ __attribute__((aligned(16))) _Float16 sS2[4 * 32 * SS4]; // 22.5 KB

  const int bh = blockIdx.y;
  const int b = bh >> 4, h = bh & 15;
  const int qtA = blockIdx.x;        // 0..15 (small half)
  const int qtB = 31 - qtA;          // 16..31 (large half)
  const int tid = threadIdx.x;
  const int w = tid >> 6;
  const int lane = tid & 63;
  const int quad = lane >> 4;
  const int l16 = lane & 15;
  const int gqA = qtA * 64 + w * 16;
  const int gqB = qtB * 64 + w * 16;

  // Q A-frags (k>=16 zero-padded)
  f16x8 qfragA = {}, qfragB = {};
  if (quad < 2) {
    qfragA = *(const f16x8*)(QKV +
        (size_t)(b * LL + gqA + l16) * RQKV + h * FD + quad * 8);
    qfragB = *(const f16x8*)(QKV +
        (size_t)(b * LL + gqB + l16) * RQKV + h * FD + quad * 8);
  }

  // z-ones tile: sVt rows 64..79 (row 64 = ones for keys 0..63, rest zero)
  for (int t = tid; t < 16 * SV4; t += 256) {
    int r = t / SV4, c = t % SV4;
    sVt[64 * SV4 + t] = (_Float16)((r == 0 && c < 64) ? 1.0f : 0.0f);
  }
  __syncthreads();
  const f16x8 zf0 = *(const f16x8*)&sVt[(64 + l16) * SV4 + quad * 8];
  const f16x8 zf1 = *(const f16x8*)&sVt[(64 + l16) * SV4 + 32 + quad * 8];

  f32x4 oaccA[4], oaccB[4];
  f32x4 zaccA = (f32x4){0.f, 0.f, 0.f, 0.f};
  f32x4 zaccB = (f32x4){0.f, 0.f, 0.f, 0.f};
#pragma unroll
  for (int nt = 0; nt < 4; nt++) {
    oaccA[nt] = (f32x4){0.f, 0.f, 0.f, 0.f};
    oaccB[nt] = (f32x4){0.f, 0.f, 0.f, 0.f};
  }

  _Float16* sS2B = sS2 + w * 32 * SS4;       // rows 0..15 of wave strip
  _Float16* sS2A = sS2B + 16 * SS4;          // rows 16..31

  const int ktiles = qtB + 1;

  // staging assignments + prefetch registers
  const int skey = tid >> 2, sfg = (tid & 3) * 4;
  uint2 kreg;
  f16x8 vreg0, vreg1;
  auto LOAD = [&](int kt) {
    kreg = *(const uint2*)(QKV +
        (size_t)(b * LL + kt * 64 + skey) * RQKV + 256 + h * FD + sfg);
    const _Float16* vp = QKV +
        (size_t)(b * LL + kt * 64 + lane) * RQKV + 512 + h * HD + w * 16;
    vreg0 = *(const f16x8*)vp;
    vreg1 = *(const f16x8*)(vp + 8);
  };
  LOAD(0);

  for (int kt = 0; kt < ktiles; kt++) {
    __syncthreads();  // previous iteration's LDS readers done
    *(uint2*)&sK[skey * SK4 + sfg] = kreg;
#pragma unroll
    for (int t = 0; t < 8; t++) sVt[(w * 16 + t) * SV4 + lane] = vreg0[t];
#pragma unroll
    for (int t = 0; t < 8; t++) sVt[(w * 16 + 8 + t) * SV4 + lane] = vreg1[t];
    __syncthreads();
    if (kt + 1 < ktiles) LOAD(kt + 1);  // prefetch overlaps compute below

    const int k0 = kt * 64;
    const bool activeA = (kt <= qtA);   // block-uniform

    // K B-frags, shared by both halves
    f16x8 kf[4];
#pragma unroll
    for (int nt = 0; nt < 4; nt++) {
      f16x8 f = {};
      if (quad < 2) f = *(const f16x8*)&sK[(nt * 16 + l16) * SK4 + quad * 8];
      kf[nt] = f;
    }

    // ---- B-half S^2 ----
    {
      const bool mask = (kt == qtB);
#pragma unroll
      for (int nt = 0; nt < 4; nt++) {
        f32x4 s = __builtin_amdgcn_mfma_f32_16x16x32_f16(
            qfragB, kf[nt], (f32x4){0.f, 0.f, 0.f, 0.f}, 0, 0, 0);
        const int gk = k0 + nt * 16 + l16;
#pragma unroll
        for (int r = 0; r < 4; r++) {
          float sv = s[r] * s[r] * 2.0f;
          if (mask) sv = (gk <= gqB + quad * 4 + r) ? sv : 0.0f;
          sS2B[(quad * 4 + r) * SS4 + nt * 16 + l16] = (_Float16)sv;
        }
      }
    }
    // ---- A-half S^2 ----
    if (activeA) {
      const bool mask = (kt == qtA);
#pragma unroll
      for (int nt = 0; nt < 4; nt++) {
        f32x4 s = __builtin_amdgcn_mfma_f32_16x16x32_f16(
            qfragA, kf[nt], (f32x4){0.f, 0.f, 0.f, 0.f}, 0, 0, 0);
        const int gk = k0 + nt * 16 + l16;
#pragma unroll
        for (int r = 0; r < 4; r++) {
          float sv = s[r] * s[r] * 2.0f;
          if (mask) sv = (gk <= gqA + quad * 4 + r) ? sv : 0.0f;
          sS2A[(quad * 4 + r) * SS4 + nt * 16 + l16] = (_Float16)sv;
        }
      }
    }
    // wave-private LDS round trip: drain writes before frag reads
    __asm__ volatile("s_waitcnt lgkmcnt(0)" ::: "memory");

    f16x8 afB0 = *(const f16x8*)&sS2B[l16 * SS4 + quad * 8];
    f16x8 afB1 = *(const f16x8*)&sS2B[l16 * SS4 + 32 + quad * 8];
    f16x8 afA0 = {}, afA1 = {};
    if (activeA) {
      afA0 = *(const f16x8*)&sS2A[l16 * SS4 + quad * 8];
      afA1 = *(const f16x8*)&sS2A[l16 * SS4 + 32 + quad * 8];
    }

    // O += S2 @ V ; z += S2 @ ones  (vf frags shared by both halves)
#pragma unroll
    for (int nt = 0; nt < 4; nt++) {
      f16x8 vf0 = *(const f16x8*)&sVt[(nt * 16 + l16) * SV4 + quad * 8];
      f16x8 vf1 = *(const f16x8*)&sVt[(nt * 16 + l16) * SV4 + 32 + quad * 8];
      oaccB[nt] = __builtin_amdgcn_mfma_f32_16x16x32_f16(afB0, vf0, oaccB[nt], 0, 0, 0);
      oaccB[nt] = __builtin_amdgcn_mfma_f32_16x16x32_f16(afB1, vf1, oaccB[nt], 0, 0, 0);
      if (activeA) {
        oaccA[nt] = __builtin_amdgcn_mfma_f32_16x16x32_f16(afA0, vf0, oaccA[nt], 0, 0, 0);
        oaccA[nt] = __builtin_amdgcn_mfma_f32_16x16x32_f16(afA1, vf1, oaccA[nt], 0, 0, 0);
      }
    }
    zaccB = __builtin_amdgcn_mfma_f32_16x16x32_f16(afB0, zf0, zaccB, 0, 0, 0);
    zaccB = __builtin_amdgcn_mfma_f32_16x16x32_f16(afB1, zf1, zaccB, 0, 0, 0);
    if (activeA) {
      zaccA = __builtin_amdgcn_mfma_f32_16x16x32_f16(afA0, zf0, zaccA, 0, 0, 0);
      zaccA = __builtin_amdgcn_mfma_f32_16x16x32_f16(afA1, zf1, zaccA, 0, 0, 0);
    }
  }

  // epilogue: z in col 0 (lane quad*16); broadcast, invert, store both halves
  {
    float rz[4];
#pragma unroll
    for (int r = 0; r < 4; r++) {
      float zz = __shfl(zaccB[r], lane & 48);
      rz[r] = 1.0f / (zz + 32.0f * EPS);
    }
#pragma unroll
    for (int nt = 0; nt < 4; nt++)
#pragma unroll
      for (int r = 0; r < 4; r++) {
        const int gq = gqB + quad * 4 + r;
        O[(size_t)(b * LL + gq) * (HH * HD) + h * HD + nt * 16 + l16] =
            (_Float16)(oaccB[nt][r] * rz[r]);
      }
  }
  {
    float rz[4];
#pragma unroll
    for (int r = 0; r < 4; r++) {
      float zz = __shfl(zaccA[r], lane & 48);
      rz[r] = 1.0f / (zz + 32.0f * EPS);
    }
#pragma unroll
    for (int nt = 0; nt < 4; nt++)
#pragma unroll
      for (int r = 0; r < 4; r++) {
        const int gq = gqA + quad * 4 + r;
        O[(size_t)(b * LL + gq) * (HH * HD) + h * HD + nt * 16 + l16] =
            (_Float16)(oaccA[nt][r] * rz[r]);
      }
  }
}

// ---------------------------------------------------------------------------
// early_qkv: QKVe[8][1536] = hs_early[8][1024] @ [Wq|Wk|Wv], ALL fp32.
// (Early rows must come from fp32 inputs: fp16-sourced q,k give |ds|~4e-4,
// which s^2/(z+eps) amplifies to ~0.1 output error on low-z rows.)
// ---------------------------------------------------------------------------
__global__ __launch_bounds__(256) void early_qkv(
    const float* __restrict__ hs, const float* __restrict__ Wq,
    const float* __restrict__ Wk, const float* __restrict__ Wv,
    float* __restrict__ QKVe) {
  __shared__ float sHS[8][DD];
  __shared__ float part[8][8][32];
  const int tid = threadIdx.x;
  const int kg = tid >> 5, c = tid & 31;
  const int c0 = blockIdx.x * 32;

  for (int i = tid; i < 8 * (DD / 4); i += 256) {
    int e = i / (DD / 4), col4 = (i % (DD / 4)) * 4;
    int b = e >> 2, r = e & 3;
    *(float4*)&sHS[e][col4] =
        *(const float4*)(hs + (size_t)(b * LL + r) * DD + col4);
  }
  __syncthreads();

  const float* W;
  int col, ncol;
  if (c0 < 256) { W = Wq; col = c0 + c; ncol = 256; }
  else if (c0 < 512) { W = Wk; col = (c0 - 256) + c; ncol = 256; }
  else { W = Wv; col = (c0 - 512) + c; ncol = 1024; }

  float acc[8] = {};
  const int d0 = kg * 128;
#pragma unroll 4
  for (int d = d0; d < d0 + 128; d++) {
    float wv = W[(size_t)d * ncol + col];
#pragma unroll
    for (int e = 0; e < 8; e++) acc[e] += sHS[e][d] * wv;
  }
#pragma unroll
  for (int e = 0; e < 8; e++) part[kg][e][c] = acc[e];
  __syncthreads();

  {
    int e = tid >> 5;
    float t = 0.f;
#pragma unroll
    for (int g = 0; g < 8; g++) t += part[g][e][c];
    QKVe[(size_t)e * RQKV + c0 + c] = t;
  }
}

// ---------------------------------------------------------------------------
// fix_final: exact fp32 ratio for the first NFIX positions per (b,h).
// ---------------------------------------------------------------------------
__global__ __launch_bounds__(256) void fix_final(
    const float* __restrict__ QKVe, _Float16* __restrict__ Oatt) {
  const int b = blockIdx.x >> 4, h = blockIdx.x & 15;
  const int tid = threadIdx.x;
  const int p = tid >> 6, d = tid & 63;

  float num = 0.f, z = 0.f;
  const float* qrow = QKVe + (size_t)(b * 4 + p) * RQKV + h * FD;
  for (int j = 0; j <= p; j++) {
    const float* krow = QKVe + (size_t)(b * 4 + j) * RQKV + 256 + h * FD;
    float s = 0.f;
#pragma unroll
    for (int f = 0; f < FD; f++) s += qrow[f] * krow[f];
    s *= 0.25f;
    s = s * s;
    z += s;
    num += s * QKVe[(size_t)(b * 4 + j) * RQKV + 512 + h * HD + d];
  }
  Oatt[(size_t)(b * LL + p) * (HH * HD) + h * HD + d] =
      (_Float16)(num / (z + EPS));
}

// ---------------------------------------------------------------------------
// Launch
// ---------------------------------------------------------------------------
extern "C" void kernel_launch(void* const* d_in, const int* in_sizes, int n_in,
                              void* d_out, int out_size, void* d_ws, size_t ws_size,
                              hipStream_t stream) {
  const float* hs = (const float*)d_in[0];  // [4096, 1024]
  const float* Wq = (const float*)d_in[1];  // [1024, 256]
  const float* Wk = (const float*)d_in[2];  // [1024, 256]
  const float* Wv = (const float*)d_in[3];  // [1024, 1024]
  const float* Wo = (const float*)d_in[4];  // [1024, 1024]
  float* out = (float*)d_out;               // [4096, 1024]

  char* ws = (char*)d_ws;
  _Float16* WqkvT = (_Float16*)ws;                    // [1536][1024] = 3 MiB
  _Float16* WoT   = (_Float16*)(ws + (3ull << 20));   // [1024][1024] = 2 MiB
  _Float16* QKV   = (_Float16*)(ws + (8ull << 20));   // [4096][1536] = 12 MiB
  _Float16* Oatt  = (_Float16*)(ws + (20ull << 20));  // [4096][1024] = 8 MiB
  float*    QKVe  = (float*)(ws + (28ull << 20));     // [8][1536] fp32

  const int M = BB * LL;  // 4096

  transpose_cast<<<dim3(256 / 32, DD / 32), 256, 0, stream>>>(Wq, WqkvT, DD, 256);
  transpose_cast<<<dim3(256 / 32, DD / 32), 256, 0, stream>>>(Wk, WqkvT + 256 * DD, DD, 256);
  transpose_cast<<<dim3(DD / 32, DD / 32), 256, 0, stream>>>(Wv, WqkvT + 512 * DD, DD, DD);
  transpose_cast<<<dim3(DD / 32, DD / 32), 256, 0, stream>>>(Wo, WoT, DD, DD);

  early_qkv<<<dim3(RQKV / 32), 256, 0, stream>>>(hs, Wq, Wk, Wv, QKVe);

  gemm_tn<float, _Float16><<<dim3(RQKV / 128, M / 128), 256, 0, stream>>>(
      hs, WqkvT, QKV, M, RQKV, DD);

  // paired complementary q-tiles: 512 perfectly-balanced blocks
  attn_mfma4<<<dim3(LL / 128, BB * HH), 256, 0, stream>>>(QKV, Oatt);

  fix_final<<<dim3(BB * HH), 256, 0, stream>>>(QKVe, Oatt);

  gemm_tn<_Float16, float><<<dim3(DD / 128, M / 128), 256, 0, stream>>>(
      Oatt, WoT, out, M, DD, DD);
}

// Round 11
// 181.911 us; speedup vs baseline: 3.2722x; 1.0391x over previous
//
#include <hip/hip_runtime.h>
#include <hip/hip_bf16.h>

// Problem constants
#define BB 2
#define LL 2048
#define DD 1024
#define HH 16
#define FD 16
#define HD 64
#define EPS 1e-5f
#define RQKV 1536   // fused QKV row stride (256 Q + 256 K + 1024 V)
#define NFIX 4      // first NFIX positions per (b,h) recomputed in fp32 (low-z rows)

typedef __attribute__((ext_vector_type(4))) float f32x4;
typedef __attribute__((ext_vector_type(8))) _Float16 f16x8;
typedef __attribute__((ext_vector_type(4))) _Float16 f16x4;

// ---------------------------------------------------------------------------
// cast_hs: fp32 -> fp16, 16 elems/thread. n must be divisible by 16.
// ---------------------------------------------------------------------------
__global__ __launch_bounds__(256) void cast_hs(
    const float* __restrict__ src, _Float16* __restrict__ dst, int n) {
  int idx = (blockIdx.x * 256 + threadIdx.x) * 16;
  if (idx >= n) return;
#pragma unroll
  for (int half = 0; half < 2; half++) {
    float4 a = *(const float4*)(src + idx + half * 8);
    float4 b = *(const float4*)(src + idx + half * 8 + 4);
    f16x8 p = {(_Float16)a.x, (_Float16)a.y, (_Float16)a.z, (_Float16)a.w,
               (_Float16)b.x, (_Float16)b.y, (_Float16)b.z, (_Float16)b.w};
    *(f16x8*)(dst + idx + half * 8) = p;
  }
}

// ---------------------------------------------------------------------------
// Fused QKV weight transpose+cast: [Wq|Wk|Wv] fp32 [K][ncol] -> WqkvT fp16
// [1536][1024]. Flat grid: bid = kt*48 + ct; ct selects source matrix/cols.
// ---------------------------------------------------------------------------
__global__ __launch_bounds__(256) void transpose_qkv(
    const float* __restrict__ Wq, const float* __restrict__ Wk,
    const float* __restrict__ Wv, _Float16* __restrict__ dst) {
  __shared__ _Float16 s[32][40];
  const int ct = blockIdx.x % 48, kt = blockIdx.x / 48;
  const float* src;
  int n0, ncol, drow;
  if (ct < 8) { src = Wq; n0 = ct * 32; ncol = 256; drow = n0; }
  else if (ct < 16) { src = Wk; n0 = (ct - 8) * 32; ncol = 256; drow = 256 + n0; }
  else { src = Wv; n0 = (ct - 16) * 32; ncol = 1024; drow = 512 + n0; }
  const int k0 = kt * 32;
  const int tid = threadIdx.x;
  {
    int r = tid >> 3, c = (tid & 7) * 4;
    float4 v = *(const float4*)(src + (size_t)(k0 + r) * ncol + n0 + c);
    f16x4 p = {(_Float16)v.x, (_Float16)v.y, (_Float16)v.z, (_Float16)v.w};
    *(f16x4*)&s[r][c] = p;
  }
  __syncthreads();
  {
    int n = tid >> 3, kk = (tid & 7) * 4;
    f16x4 o = {s[kk + 0][n], s[kk + 1][n], s[kk + 2][n], s[kk + 3][n]};
    *(f16x4*)(dst + (size_t)(drow + n) * DD + k0 + kk) = o;
  }
}

// ---------------------------------------------------------------------------
// Wo transpose+cast (single matrix): fp32 [K][N] -> fp16 [N][K].
// ---------------------------------------------------------------------------
__global__ __launch_bounds__(256) void transpose_cast(
    const float* __restrict__ src, _Float16* __restrict__ dst, int K, int N) {
  __shared__ _Float16 s[32][40];
  const int n0 = blockIdx.x * 32, k0 = blockIdx.y * 32;
  const int tid = threadIdx.x;
  {
    int r = tid >> 3, c = (tid & 7) * 4;
    float4 v = *(const float4*)(src + (size_t)(k0 + r) * N + n0 + c);
    f16x4 p = {(_Float16)v.x, (_Float16)v.y, (_Float16)v.z, (_Float16)v.w};
    *(f16x4*)&s[r][c] = p;
  }
  __syncthreads();
  {
    int n = tid >> 3, kk = (tid & 7) * 4;
    f16x4 o = {s[kk + 0][n], s[kk + 1][n], s[kk + 2][n], s[kk + 3][n]};
    *(f16x4*)(dst + (size_t)(n0 + n) * K + k0 + kk) = o;
  }
}

// ---------------------------------------------------------------------------
// fp16 MFMA GEMM: C[M,N] = A[M,K] @ Bt[N,K]^T. 128x128 tile, BK=64, 4 waves.
// 32 MFMAs between barrier pairs; register prefetch of the next 64-K slab
// (4+4 b128 loads) overlaps global latency with MFMA. LDT=72: frag reads
// (4r+4q+16s mod 32) are 2-way = free.
// ---------------------------------------------------------------------------
template <typename OutT>
__global__ __launch_bounds__(256) void gemm_f16(
    const _Float16* __restrict__ A, const _Float16* __restrict__ Bt,
    OutT* __restrict__ C, int M, int N, int K) {
  constexpr int LDT = 72;
  __shared__ __attribute__((aligned(16))) _Float16 sA[128 * LDT];  // 18 KB
  __shared__ __attribute__((aligned(16))) _Float16 sB[128 * LDT];  // 18 KB
  const int tid = threadIdx.x;
  const int m0 = blockIdx.y * 128, n0 = blockIdx.x * 128;
  const int w = tid >> 6, lane = tid & 63, quad = lane >> 4, l16 = lane & 15;
  const int wm = (w >> 1) * 64, wn = (w & 1) * 64;

  // staging: 2 threads per row, 32 fp16 (4 chunks) each
  const int sr = tid >> 1, sh = (tid & 1) * 32;
  const _Float16* Ag = A + (size_t)(m0 + sr) * K + sh;
  const _Float16* Bg = Bt + (size_t)(n0 + sr) * K + sh;
  _Float16* sAw = &sA[sr * LDT + sh];
  _Float16* sBw = &sB[sr * LDT + sh];

  f32x4 acc[4][4];
#pragma unroll
  for (int i = 0; i < 4; i++)
#pragma unroll
    for (int j = 0; j < 4; j++) acc[i][j] = (f32x4){0.f, 0.f, 0.f, 0.f};

  f16x8 ar[4], br[4];
  auto LOAD = [&](int k0) {
#pragma unroll
    for (int i = 0; i < 4; i++) {
      ar[i] = *(const f16x8*)(Ag + k0 + i * 8);
      br[i] = *(const f16x8*)(Bg + k0 + i * 8);
    }
  };
  LOAD(0);

  for (int k0 = 0; k0 < K; k0 += 64) {
    __syncthreads();
#pragma unroll
    for (int i = 0; i < 4; i++) {
      *(f16x8*)(sAw + i * 8) = ar[i];
      *(f16x8*)(sBw + i * 8) = br[i];
    }
    __syncthreads();
    if (k0 + 64 < K) LOAD(k0 + 64);  // prefetch overlaps the 32 MFMAs below

#pragma unroll
    for (int s = 0; s < 2; s++) {
      f16x8 af[4], bf[4];
#pragma unroll
      for (int i = 0; i < 4; i++)
        af[i] = *(const f16x8*)&sA[(wm + i * 16 + l16) * LDT + s * 32 + quad * 8];
#pragma unroll
      for (int j = 0; j < 4; j++)
        bf[j] = *(const f16x8*)&sB[(wn + j * 16 + l16) * LDT + s * 32 + quad * 8];
#pragma unroll
      for (int i = 0; i < 4; i++)
#pragma unroll
        for (int j = 0; j < 4; j++)
          acc[i][j] = __builtin_amdgcn_mfma_f32_16x16x32_f16(af[i], bf[j], acc[i][j], 0, 0, 0);
    }
  }

#pragma unroll
  for (int i = 0; i < 4; i++)
#pragma unroll
    for (int j = 0; j < 4; j++)
#pragma unroll
      for (int r = 0; r < 4; r++) {
        const int row = m0 + wm + i * 16 + quad * 4 + r;
        const int col = n0 + wn + j * 16 + l16;
        C[(size_t)row * N + col] = (OutT)acc[i][j][r];
      }
}

// ---------------------------------------------------------------------------
// MFMA causal quadratic attention, v4: paired complementary query tiles.
// (unchanged from round 10 — see its header comment)
// ---------------------------------------------------------------------------
#define SK4 24
#define SV4 88
#define SS4 88

__global__ __launch_bounds__(256) void attn_mfma4(
    const _Float16* __restrict__ QKV, _Float16* __restrict__ O) {
  __shared__ __attribute__((aligned(16))) _Float16 sK[64 * SK4];
  __shared__ __attribute__((aligned(16))) _Float16 sVt[80 * SV4];
  __shared__ __attribute__((aligned(16))) _Float16 sS2[4 * 32 * SS4];

  const int bh = blockIdx.y;
  const int b = bh >> 4, h = bh & 15;
  const int qtA = blockIdx.x;
  const int qtB = 31 - qtA;
  const int tid = threadIdx.x;
  const int w = tid >> 6;
  const int lane = tid & 63;
  const int quad = lane >> 4;
  const int l16 = lane & 15;
  const int gqA = qtA * 64 + w * 16;
  const int gqB = qtB * 64 + w * 16;

  f16x8 qfragA = {}, qfragB = {};
  if (quad < 2) {
    qfragA = *(const f16x8*)(QKV +
        (size_t)(b * LL + gqA + l16) * RQKV + h * FD + quad * 8);
    qfragB = *(const f16x8*)(QKV +
        (size_t)(b * LL + gqB + l16) * RQKV + h * FD + quad * 8);
  }

  for (int t = tid; t < 16 * SV4; t += 256) {
    int r = t / SV4, c = t % SV4;
    sVt[64 * SV4 + t] = (_Float16)((r == 0 && c < 64) ? 1.0f : 0.0f);
  }
  __syncthreads();
  const f16x8 zf0 = *(const f16x8*)&sVt[(64 + l16) * SV4 + quad * 8];
  const f16x8 zf1 = *(const f16x8*)&sVt[(64 + l16) * SV4 + 32 + quad * 8];

  f32x4 oaccA[4], oaccB[4];
  f32x4 zaccA = (f32x4){0.f, 0.f, 0.f, 0.f};
  f32x4 zaccB = (f32x4){0.f, 0.f, 0.f, 0.f};
#pragma unroll
  for (int nt = 0; nt < 4; nt++) {
    oaccA[nt] = (f32x4){0.f, 0.f, 0.f, 0.f};
    oaccB[nt] = (f32x4){0.f, 0.f, 0.f, 0.f};
  }

  _Float16* sS2B = sS2 + w * 32 * SS4;
  _Float16* sS2A = sS2B + 16 * SS4;

  const int ktiles = qtB + 1;

  const int skey = tid >> 2, sfg = (tid & 3) * 4;
  uint2 kreg;
  f16x8 vreg0, vreg1;
  auto LOAD = [&](int kt) {
    kreg = *(const uint2*)(QKV +
        (size_t)(b * LL + kt * 64 + skey) * RQKV + 256 + h * FD + sfg);
    const _Float16* vp = QKV +
        (size_t)(b * LL + kt * 64 + lane) * RQKV + 512 + h * HD + w * 16;
    vreg0 = *(const f16x8*)vp;
    vreg1 = *(const f16x8*)(vp + 8);
  };
  LOAD(0);

  for (int kt = 0; kt < ktiles; kt++) {
    __syncthreads();
    *(uint2*)&sK[skey * SK4 + sfg] = kreg;
#pragma unroll
    for (int t = 0; t < 8; t++) sVt[(w * 16 + t) * SV4 + lane] = vreg0[t];
#pragma unroll
    for (int t = 0; t < 8; t++) sVt[(w * 16 + 8 + t) * SV4 + lane] = vreg1[t];
    __syncthreads();
    if (kt + 1 < ktiles) LOAD(kt + 1);

    const int k0 = kt * 64;
    const bool activeA = (kt <= qtA);

    f16x8 kf[4];
#pragma unroll
    for (int nt = 0; nt < 4; nt++) {
      f16x8 f = {};
      if (quad < 2) f = *(const f16x8*)&sK[(nt * 16 + l16) * SK4 + quad * 8];
      kf[nt] = f;
    }

    {
      const bool mask = (kt == qtB);
#pragma unroll
      for (int nt = 0; nt < 4; nt++) {
        f32x4 s = __builtin_amdgcn_mfma_f32_16x16x32_f16(
            qfragB, kf[nt], (f32x4){0.f, 0.f, 0.f, 0.f}, 0, 0, 0);
        const int gk = k0 + nt * 16 + l16;
#pragma unroll
        for (int r = 0; r < 4; r++) {
          float sv = s[r] * s[r] * 2.0f;
          if (mask) sv = (gk <= gqB + quad * 4 + r) ? sv : 0.0f;
          sS2B[(quad * 4 + r) * SS4 + nt * 16 + l16] = (_Float16)sv;
        }
      }
    }
    if (activeA) {
      const bool mask = (kt == qtA);
#pragma unroll
      for (int nt = 0; nt < 4; nt++) {
        f32x4 s = __builtin_amdgcn_mfma_f32_16x16x32_f16(
            qfragA, kf[nt], (f32x4){0.f, 0.f, 0.f, 0.f}, 0, 0, 0);
        const int gk = k0 + nt * 16 + l16;
#pragma unroll
        for (int r = 0; r < 4; r++) {
          float sv = s[r] * s[r] * 2.0f;
          if (mask) sv = (gk <= gqA + quad * 4 + r) ? sv : 0.0f;
          sS2A[(quad * 4 + r) * SS4 + nt * 16 + l16] = (_Float16)sv;
        }
      }
    }
    __asm__ volatile("s_waitcnt lgkmcnt(0)" ::: "memory");

    f16x8 afB0 = *(const f16x8*)&sS2B[l16 * SS4 + quad * 8];
    f16x8 afB1 = *(const f16x8*)&sS2B[l16 * SS4 + 32 + quad * 8];
    f16x8 afA0 = {}, afA1 = {};
    if (activeA) {
      afA0 = *(const f16x8*)&sS2A[l16 * SS4 + quad * 8];
      afA1 = *(const f16x8*)&sS2A[l16 * SS4 + 32 + quad * 8];
    }

#pragma unroll
    for (int nt = 0; nt < 4; nt++) {
      f16x8 vf0 = *(const f16x8*)&sVt[(nt * 16 + l16) * SV4 + quad * 8];
      f16x8 vf1 = *(const f16x8*)&sVt[(nt * 16 + l16) * SV4 + 32 + quad * 8];
      oaccB[nt] = __builtin_amdgcn_mfma_f32_16x16x32_f16(afB0, vf0, oaccB[nt], 0, 0, 0);
      oaccB[nt] = __builtin_amdgcn_mfma_f32_16x16x32_f16(afB1, vf1, oaccB[nt], 0, 0, 0);
      if (activeA) {
        oaccA[nt] = __builtin_amdgcn_mfma_f32_16x16x32_f16(afA0, vf0, oaccA[nt], 0, 0, 0);
        oaccA[nt] = __builtin_amdgcn_mfma_f32_16x16x32_f16(afA1, vf1, oaccA[nt], 0, 0, 0);
      }
    }
    zaccB = __builtin_amdgcn_mfma_f32_16x16x32_f16(afB0, zf0, zaccB, 0, 0, 0);
    zaccB = __builtin_amdgcn_mfma_f32_16x16x32_f16(afB1, zf1, zaccB, 0, 0, 0);
    if (activeA) {
      zaccA = __builtin_amdgcn_mfma_f32_16x16x32_f16(afA0, zf0, zaccA, 0, 0, 0);
      zaccA = __builtin_amdgcn_mfma_f32_16x16x32_f16(afA1, zf1, zaccA, 0, 0, 0);
    }
  }

  {
    float rz[4];
#pragma unroll
    for (int r = 0; r < 4; r++) {
      float zz = __shfl(zaccB[r], lane & 48);
      rz[r] = 1.0f / (zz + 32.0f * EPS);
    }
#pragma unroll
    for (int nt = 0; nt < 4; nt++)
#pragma unroll
      for (int r = 0; r < 4; r++) {
        const int gq = gqB + quad * 4 + r;
        O[(size_t)(b * LL + gq) * (HH * HD) + h * HD + nt * 16 + l16] =
            (_Float16)(oaccB[nt][r] * rz[r]);
      }
  }
  {
    float rz[4];
#pragma unroll
    for (int r = 0; r < 4; r++) {
      float zz = __shfl(zaccA[r], lane & 48);
      rz[r] = 1.0f / (zz + 32.0f * EPS);
    }
#pragma unroll
    for (int nt = 0; nt < 4; nt++)
#pragma unroll
      for (int r = 0; r < 4; r++) {
        const int gq = gqA + quad * 4 + r;
        O[(size_t)(b * LL + gq) * (HH * HD) + h * HD + nt * 16 + l16] =
            (_Float16)(oaccA[nt][r] * rz[r]);
      }
  }
}

// ---------------------------------------------------------------------------
// early_qkv: QKVe[8][1536] = hs_early[8][1024] @ [Wq|Wk|Wv], ALL fp32.
// ---------------------------------------------------------------------------
__global__ __launch_bounds__(256) void early_qkv(
    const float* __restrict__ hs, const float* __restrict__ Wq,
    const float* __restrict__ Wk, const float* __restrict__ Wv,
    float* __restrict__ QKVe) {
  __shared__ float sHS[8][DD];
  __shared__ float part[8][8][32];
  const int tid = threadIdx.x;
  const int kg = tid >> 5, c = tid & 31;
  const int c0 = blockIdx.x * 32;

  for (int i = tid; i < 8 * (DD / 4); i += 256) {
    int e = i / (DD / 4), col4 = (i % (DD / 4)) * 4;
    int b = e >> 2, r = e & 3;
    *(float4*)&sHS[e][col4] =
        *(const float4*)(hs + (size_t)(b * LL + r) * DD + col4);
  }
  __syncthreads();

  const float* W;
  int col, ncol;
  if (c0 < 256) { W = Wq; col = c0 + c; ncol = 256; }
  else if (c0 < 512) { W = Wk; col = (c0 - 256) + c; ncol = 256; }
  else { W = Wv; col = (c0 - 512) + c; ncol = 1024; }

  float acc[8] = {};
  const int d0 = kg * 128;
#pragma unroll 4
  for (int d = d0; d < d0 + 128; d++) {
    float wv = W[(size_t)d * ncol + col];
#pragma unroll
    for (int e = 0; e < 8; e++) acc[e] += sHS[e][d] * wv;
  }
#pragma unroll
  for (int e = 0; e < 8; e++) part[kg][e][c] = acc[e];
  __syncthreads();

  {
    int e = tid >> 5;
    float t = 0.f;
#pragma unroll
    for (int g = 0; g < 8; g++) t += part[g][e][c];
    QKVe[(size_t)e * RQKV + c0 + c] = t;
  }
}

// ---------------------------------------------------------------------------
// fix_final: exact fp32 ratio for the first NFIX positions per (b,h).
// ---------------------------------------------------------------------------
__global__ __launch_bounds__(256) void fix_final(
    const float* __restrict__ QKVe, _Float16* __restrict__ Oatt) {
  const int b = blockIdx.x >> 4, h = blockIdx.x & 15;
  const int tid = threadIdx.x;
  const int p = tid >> 6, d = tid & 63;

  float num = 0.f, z = 0.f;
  const float* qrow = QKVe + (size_t)(b * 4 + p) * RQKV + h * FD;
  for (int j = 0; j <= p; j++) {
    const float* krow = QKVe + (size_t)(b * 4 + j) * RQKV + 256 + h * FD;
    float s = 0.f;
#pragma unroll
    for (int f = 0; f < FD; f++) s += qrow[f] * krow[f];
    s *= 0.25f;
    s = s * s;
    z += s;
    num += s * QKVe[(size_t)(b * 4 + j) * RQKV + 512 + h * HD + d];
  }
  Oatt[(size_t)(b * LL + p) * (HH * HD) + h * HD + d] =
      (_Float16)(num / (z + EPS));
}

// ---------------------------------------------------------------------------
// Launch
// ---------------------------------------------------------------------------
extern "C" void kernel_launch(void* const* d_in, const int* in_sizes, int n_in,
                              void* d_out, int out_size, void* d_ws, size_t ws_size,
                              hipStream_t stream) {
  const float* hs = (const float*)d_in[0];  // [4096, 1024]
  const float* Wq = (const float*)d_in[1];  // [1024, 256]
  const float* Wk = (const float*)d_in[2];  // [1024, 256]
  const float* Wv = (const float*)d_in[3];  // [1024, 1024]
  const float* Wo = (const float*)d_in[4];  // [1024, 1024]
  float* out = (float*)d_out;               // [4096, 1024]

  char* ws = (char*)d_ws;
  _Float16* WqkvT = (_Float16*)ws;                    // [1536][1024] = 3 MiB
  _Float16* WoT   = (_Float16*)(ws + (3ull << 20));   // [1024][1024] = 2 MiB
  _Float16* HS16  = (_Float16*)(ws + (5ull << 20));   // [4096][1024] = 8 MiB
  _Float16* QKV   = (_Float16*)(ws + (13ull << 20));  // [4096][1536] = 12 MiB
  _Float16* Oatt  = (_Float16*)(ws + (25ull << 20));  // [4096][1024] = 8 MiB
  float*    QKVe  = (float*)(ws + (33ull << 20));     // [8][1536] fp32

  const int M = BB * LL;  // 4096

  cast_hs<<<dim3(M * DD / (256 * 16)), 256, 0, stream>>>(hs, HS16, M * DD);
  transpose_qkv<<<dim3(48 * 32), 256, 0, stream>>>(Wq, Wk, Wv, WqkvT);
  transpose_cast<<<dim3(DD / 32, DD / 32), 256, 0, stream>>>(Wo, WoT, DD, DD);

  early_qkv<<<dim3(RQKV / 32), 256, 0, stream>>>(hs, Wq, Wk, Wv, QKVe);

  gemm_f16<_Float16><<<dim3(RQKV / 128, M / 128), 256, 0, stream>>>(
      HS16, WqkvT, QKV, M, RQKV, DD);

  attn_mfma4<<<dim3(LL / 128, BB * HH), 256, 0, stream>>>(QKV, Oatt);

  fix_final<<<dim3(BB * HH), 256, 0, stream>>>(QKVe, Oatt);

  gemm_f16<float><<<dim3(DD / 128, M / 128), 256, 0, stream>>>(
      Oatt, WoT, out, M, DD, DD);
}